// Round 2
// baseline (462.462 us; speedup 1.0000x reference)
//
#include <hip/hip_runtime.h>

#define Bn 4
#define Sn 1024
#define En 1024
#define Wn 768
#define Hn 12
#define Dn 64
#define XE ((size_t)Bn * Sn * Wn)   // 3,145,728

typedef __attribute__((ext_vector_type(8))) short short8;
typedef __attribute__((ext_vector_type(4))) short short4v;
typedef __attribute__((ext_vector_type(4))) float floatx4;

#define MFMA16(A, B, C) __builtin_amdgcn_mfma_f32_16x16x32_bf16(A, B, C, 0, 0, 0)

__device__ __forceinline__ unsigned short f2bf_rn(float f) {
    unsigned int u = __float_as_uint(f);
    unsigned int r = u + 0x7fffu + ((u >> 16) & 1u);
    return (unsigned short)(r >> 16);
}
__device__ __forceinline__ float bf2f(unsigned short h) {
    return __uint_as_float(((unsigned int)h) << 16);
}

__device__ __forceinline__ void gload_lds16(const unsigned short* g, unsigned short* l) {
    __builtin_amdgcn_global_load_lds(
        (const __attribute__((address_space(1))) void*)g,
        (__attribute__((address_space(3))) void*)l, 16, 0, 0);
}

// ---------------------------------------------------------------------------
// Fused prep: x split (3072 blocks) + 3 qkv-weight splits (1728) +
// o-weight split (576) + bias concat (9).
// ---------------------------------------------------------------------------
__global__ __launch_bounds__(256) void prep_kernel(
    const float* __restrict__ x,
    const float* __restrict__ qw, const float* __restrict__ kw,
    const float* __restrict__ vw, const float* __restrict__ ow,
    const float* __restrict__ qb, const float* __restrict__ kb,
    const float* __restrict__ vb,
    unsigned short* __restrict__ xh, unsigned short* __restrict__ xl,
    unsigned short* __restrict__ wqh, unsigned short* __restrict__ wql,
    unsigned short* __restrict__ woh, unsigned short* __restrict__ wol,
    float* __restrict__ bq)
{
    const int bx = blockIdx.x;
    const float* src; unsigned short *dh, *dl; int e;
    if (bx < 3072) {
        e = (bx * 256 + threadIdx.x) * 4;
        src = x; dh = xh; dl = xl;
    } else if (bx < 3072 + 1728) {
        int bb = bx - 3072; int which = bb / 576;
        e = ((bb - which * 576) * 256 + threadIdx.x) * 4;
        src = (which == 0) ? qw : (which == 1) ? kw : vw;
        dh = wqh + (size_t)which * Wn * Wn;
        dl = wql + (size_t)which * Wn * Wn;
    } else if (bx < 3072 + 1728 + 576) {
        e = ((bx - 3072 - 1728) * 256 + threadIdx.x) * 4;
        src = ow; dh = woh; dl = wol;
    } else {
        int t = (bx - 3072 - 1728 - 576) * 256 + threadIdx.x;
        if (t < Wn) bq[t] = qb[t];
        else if (t < 2 * Wn) bq[t] = kb[t - Wn];
        else if (t < 3 * Wn) bq[t] = vb[t - 2 * Wn];
        return;
    }
    int row = e / Wn, col = e - row * Wn;
    float4 v = *(const float4*)(src + (size_t)row * En + col);
    float f[4] = {v.x, v.y, v.z, v.w};
    short4v h, l;
    #pragma unroll
    for (int i = 0; i < 4; ++i) {
        unsigned short hh = f2bf_rn(f[i]);
        h[i] = (short)hh;
        l[i] = (short)f2bf_rn(f[i] - bf2f(hh));
    }
    *(short4v*)(dh + e) = h;
    *(short4v*)(dl + e) = l;
}

// ---------------------------------------------------------------------------
// QKV GEMM (bf16x3 MFMA for v; bf16x2 for q/k since they are rounded to
// single bf16 anyway).  q/k out: bf16 [B,H,S,D]; v out: bf16 [B,H,D,S].
// ---------------------------------------------------------------------------
__global__ __launch_bounds__(256) void qkv_mfma_kernel(
    const unsigned short* __restrict__ xh, const unsigned short* __restrict__ xl,
    const unsigned short* __restrict__ wh, const unsigned short* __restrict__ wl,
    const float* __restrict__ bq,
    unsigned short* __restrict__ qh_o, unsigned short* __restrict__ kh_o,
    unsigned short* __restrict__ vt_o)
{
    __shared__ __align__(16) unsigned short Ah[128 * 32];
    __shared__ __align__(16) unsigned short Al[128 * 32];
    __shared__ __align__(16) unsigned short Bh[128 * 32];
    __shared__ __align__(16) unsigned short Bl[128 * 32];

    const int tid = threadIdx.x;
    const int wave = tid >> 6, lane = tid & 63;
    const int quad = lane >> 4, l16 = lane & 15;
    const int m0 = blockIdx.x * 128, n0 = blockIdx.y * 128;
    const int wm = wave >> 1, wn = wave & 1;
    const int which = n0 / Wn;                 // 0=q 1=k 2=v (blocks never straddle)
    const bool full = (which == 2);

    floatx4 acc[4][4] = {};

    const unsigned short* gsrc = (wave == 0) ? xh : (wave == 1) ? xl
                               : (wave == 2) ? wh : wl;
    unsigned short* ldst = (wave == 0) ? Ah : (wave == 1) ? Al
                         : (wave == 2) ? Bh : Bl;
    const int base_row = (wave < 2) ? m0 : n0;
    const int r_in = lane >> 2;
    const int cs = (lane & 3) ^ (r_in & 3);

    for (int k0 = 0; k0 < Wn; k0 += 32) {
        if (full || wave != 1) {               // Al only needed for v-blocks
            #pragma unroll
            for (int i = 0; i < 8; ++i) {
                int r = i * 16 + r_in;
                const unsigned short* gp =
                    gsrc + (size_t)(base_row + r) * Wn + k0 + cs * 8;
                gload_lds16(gp, ldst + i * 512);
            }
        }
        __syncthreads();

        short8 afh[4], afl[4], bfh[4], bfl[4];
        #pragma unroll
        for (int t = 0; t < 4; ++t) {
            int mr = wm * 64 + t * 16 + l16;
            int ca = quad ^ (mr & 3);
            afh[t] = *(const short8*)(Ah + mr * 32 + ca * 8);
            if (full) afl[t] = *(const short8*)(Al + mr * 32 + ca * 8);
            int nr = wn * 64 + t * 16 + l16;
            int cb = quad ^ (nr & 3);
            bfh[t] = *(const short8*)(Bh + nr * 32 + cb * 8);
            bfl[t] = *(const short8*)(Bl + nr * 32 + cb * 8);
        }
        #pragma unroll
        for (int mt = 0; mt < 4; ++mt)
            #pragma unroll
            for (int nt = 0; nt < 4; ++nt) {
                acc[mt][nt] = MFMA16(afh[mt], bfh[nt], acc[mt][nt]);
                acc[mt][nt] = MFMA16(afh[mt], bfl[nt], acc[mt][nt]);
                if (full) acc[mt][nt] = MFMA16(afl[mt], bfh[nt], acc[mt][nt]);
            }
        __syncthreads();
    }

    const int b = m0 >> 10;
    #pragma unroll
    for (int nt = 0; nt < 4; ++nt) {
        const int ng = n0 + wn * 64 + nt * 16 + l16;
        const float bias = bq[ng];
        const int f = ng - which * Wn;
        const int h = f >> 6, d = f & 63;
        #pragma unroll
        for (int mt = 0; mt < 4; ++mt) {
            const int mbase = m0 + wm * 64 + mt * 16 + quad * 4;
            const int s0 = mbase & (Sn - 1);
            if (which < 2) {
                unsigned short* oq = which ? kh_o : qh_o;
                size_t idx = (((size_t)(b * Hn + h)) * Sn + s0) * Dn + d;
                #pragma unroll
                for (int r = 0; r < 4; ++r)
                    oq[idx + (size_t)r * Dn] = f2bf_rn(acc[mt][nt][r] + bias);
            } else {
                size_t idx = (((size_t)(b * Hn + h)) * Dn + d) * Sn + s0;
                short4v pk;
                #pragma unroll
                for (int r = 0; r < 4; ++r)
                    pk[r] = (short)f2bf_rn(acc[mt][nt][r] + bias);
                *(short4v*)(vt_o + idx) = pk;
            }
        }
    }
}

// ---------------------------------------------------------------------------
// Attention pass A: partial softmax denominators over a 256-key range.
// Barrier-free: bf16 Q/K fragments loaded per-lane straight from global.
// grid.x = qt*4 + ks (64), y=h, z=b -> 3072 blocks.
// ---------------------------------------------------------------------------
__global__ __launch_bounds__(256) void attn_sum_kernel(
    const unsigned short* __restrict__ qh, const unsigned short* __restrict__ kh,
    const int* __restrict__ mask, float* __restrict__ lpart)
{
    const int tid = threadIdx.x;
    const int wave = tid >> 6, lane = tid & 63;
    const int quad = lane >> 4, l16 = lane & 15;
    const int qt = blockIdx.x >> 2, ks = blockIdx.x & 3;
    const int h = blockIdx.y, b = blockIdx.z;
    const int bh = b * Hn + h;
    const size_t kvb = (size_t)bh * Sn * Dn;

    short8 qf[2];
    {
        const int s = qt * 64 + wave * 16 + l16;
        const unsigned short* qp = qh + kvb + (size_t)s * Dn + quad * 8;
        qf[0] = *(const short8*)(qp);
        qf[1] = *(const short8*)(qp + 32);
    }

    float lsum[4] = {0.f, 0.f, 0.f, 0.f};

    for (int kt = 0; kt < 4; ++kt) {
        #pragma unroll
        for (int ct = 0; ct < 4; ++ct) {
            const int key = ks * 256 + kt * 64 + ct * 16 + l16;
            const unsigned short* kp = kh + kvb + (size_t)key * Dn + quad * 8;
            short8 kf0 = *(const short8*)(kp);
            short8 kf1 = *(const short8*)(kp + 32);
            floatx4 acc = {0.f, 0.f, 0.f, 0.f};
            acc = MFMA16(qf[0], kf0, acc);
            acc = MFMA16(qf[1], kf1, acc);
            const float mv = (float)mask[b * Sn + key];
            #pragma unroll
            for (int r = 0; r < 4; ++r)
                lsum[r] += __expf(acc[r] * 0.125f) * mv;
        }
    }

    #pragma unroll
    for (int r = 0; r < 4; ++r) {
        float v = lsum[r];
        v += __shfl_xor(v, 1, 64);
        v += __shfl_xor(v, 2, 64);
        v += __shfl_xor(v, 4, 64);
        v += __shfl_xor(v, 8, 64);
        lsum[r] = v;
    }
    if (l16 == 0) {
        const int row = qt * 64 + wave * 16 + quad * 4;
        #pragma unroll
        for (int r = 0; r < 4; ++r)
            lpart[((size_t)ks * Bn * Hn + bh) * Sn + row + r] = lsum[r];
    }
}

// ---------------------------------------------------------------------------
// Attention pass B: recompute scores over ALL keys, write fp32 weights,
// accumulate full O in registers, emit bf16 hi/lo AO directly.
// grid (16, H, B) = 768 blocks.  Only LDS: wave-local 9KB P transpose buffer
// (no __syncthreads in the whole kernel).
// ---------------------------------------------------------------------------
__global__ __launch_bounds__(256) void attn_out_kernel(
    const unsigned short* __restrict__ qh, const unsigned short* __restrict__ kh,
    const unsigned short* __restrict__ vt, const int* __restrict__ mask,
    const float* __restrict__ lpart, float* __restrict__ attn,
    unsigned short* __restrict__ aoh, unsigned short* __restrict__ aol)
{
    __shared__ __align__(16) unsigned short Ps[4][16 * 72];

    const int tid = threadIdx.x;
    const int wave = tid >> 6, lane = tid & 63;
    const int quad = lane >> 4, l16 = lane & 15;
    const int qt = blockIdx.x;
    const int h = blockIdx.y, b = blockIdx.z;
    const int bh = b * Hn + h;
    const size_t kvb = (size_t)bh * Sn * Dn;
    const size_t vbase = (size_t)bh * Dn * Sn;

    short8 qf[2];
    {
        const int s = qt * 64 + wave * 16 + l16;
        const unsigned short* qp = qh + kvb + (size_t)s * Dn + quad * 8;
        qf[0] = *(const short8*)(qp);
        qf[1] = *(const short8*)(qp + 32);
    }

    const int row0 = qt * 64 + wave * 16 + quad * 4;
    float li[4];
    #pragma unroll
    for (int r = 0; r < 4; ++r) {
        float lv = 0.f;
        #pragma unroll
        for (int s4 = 0; s4 < 4; ++s4)
            lv += lpart[((size_t)s4 * Bn * Hn + bh) * Sn + row0 + r];
        li[r] = (lv > 0.f) ? 1.f / lv : 0.f;
    }

    floatx4 oacc[4] = {};

    for (int kk = 0; kk < 16; ++kk) {
        const int k0 = kk * 64;
        #pragma unroll
        for (int ct = 0; ct < 4; ++ct) {
            const int key = k0 + ct * 16 + l16;
            const unsigned short* kp = kh + kvb + (size_t)key * Dn + quad * 8;
            short8 kf0 = *(const short8*)(kp);
            short8 kf1 = *(const short8*)(kp + 32);
            floatx4 acc = {0.f, 0.f, 0.f, 0.f};
            acc = MFMA16(qf[0], kf0, acc);
            acc = MFMA16(qf[1], kf1, acc);
            const float mv = (float)mask[b * Sn + key];
            #pragma unroll
            for (int r = 0; r < 4; ++r) {
                const float p = __expf(acc[r] * 0.125f) * mv * li[r];
                attn[((size_t)bh * Sn + row0 + r) * Sn + key] = p;
                Ps[wave][(quad * 4 + r) * 72 + ct * 16 + l16] = f2bf_rn(p);
            }
        }
        // PV: wave-local Ps (in-wave LDS ordering; compiler inserts lgkmcnt)
        #pragma unroll
        for (int ksp = 0; ksp < 2; ++ksp) {
            short8 pf = *(const short8*)&Ps[wave][l16 * 72 + ksp * 32 + quad * 8];
            #pragma unroll
            for (int dt = 0; dt < 4; ++dt) {
                short8 vf = *(const short8*)(vt + vbase
                              + (size_t)(dt * 16 + l16) * Sn + k0 + ksp * 32 + quad * 8);
                oacc[dt] = MFMA16(pf, vf, oacc[dt]);
            }
        }
    }

    #pragma unroll
    for (int dt = 0; dt < 4; ++dt) {
        #pragma unroll
        for (int r = 0; r < 4; ++r) {
            const float o = oacc[dt][r];
            const unsigned short hh = f2bf_rn(o);
            const size_t idx = ((size_t)b * Sn + row0 + r) * Wn + h * Dn + dt * 16 + l16;
            aoh[idx] = hh;
            aol[idx] = f2bf_rn(o - bf2f(hh));
        }
    }
}

// ---------------------------------------------------------------------------
// O projection: 64x128 tiles -> grid (64,6) = 384 blocks.
// ---------------------------------------------------------------------------
__global__ __launch_bounds__(256) void oproj_mfma_kernel(
    const unsigned short* __restrict__ aoh, const unsigned short* __restrict__ aol,
    const unsigned short* __restrict__ wh, const unsigned short* __restrict__ wl,
    const float* __restrict__ ob, float* __restrict__ out)
{
    __shared__ __align__(16) unsigned short Ah[64 * 32];
    __shared__ __align__(16) unsigned short Al[64 * 32];
    __shared__ __align__(16) unsigned short Bh[128 * 32];
    __shared__ __align__(16) unsigned short Bl[128 * 32];

    const int tid = threadIdx.x;
    const int wave = tid >> 6, lane = tid & 63;
    const int quad = lane >> 4, l16 = lane & 15;
    const int m0 = blockIdx.x * 64, n0 = blockIdx.y * 128;
    const int wm = wave >> 1, wn = wave & 1;

    floatx4 acc[2][4] = {};

    const int r_in = lane >> 2;
    const int cs = (lane & 3) ^ (r_in & 3);

    for (int k0 = 0; k0 < Wn; k0 += 32) {
        if (wave == 0) {
            #pragma unroll
            for (int i = 0; i < 4; ++i) {
                gload_lds16(aoh + (size_t)(m0 + i * 16 + r_in) * Wn + k0 + cs * 8,
                            Ah + i * 512);
                gload_lds16(aol + (size_t)(m0 + i * 16 + r_in) * Wn + k0 + cs * 8,
                            Al + i * 512);
            }
        } else if (wave == 1) {
            #pragma unroll
            for (int i = 0; i < 8; ++i)
                gload_lds16(wh + (size_t)(n0 + i * 16 + r_in) * Wn + k0 + cs * 8,
                            Bh + i * 512);
        } else if (wave == 2) {
            #pragma unroll
            for (int i = 0; i < 8; ++i)
                gload_lds16(wl + (size_t)(n0 + i * 16 + r_in) * Wn + k0 + cs * 8,
                            Bl + i * 512);
        }
        __syncthreads();

        short8 afh[2], afl[2], bfh[4], bfl[4];
        #pragma unroll
        for (int t = 0; t < 2; ++t) {
            int mr = wm * 32 + t * 16 + l16;
            int ca = quad ^ (mr & 3);
            afh[t] = *(const short8*)(Ah + mr * 32 + ca * 8);
            afl[t] = *(const short8*)(Al + mr * 32 + ca * 8);
        }
        #pragma unroll
        for (int t = 0; t < 4; ++t) {
            int nr = wn * 64 + t * 16 + l16;
            int cb = quad ^ (nr & 3);
            bfh[t] = *(const short8*)(Bh + nr * 32 + cb * 8);
            bfl[t] = *(const short8*)(Bl + nr * 32 + cb * 8);
        }
        #pragma unroll
        for (int mt = 0; mt < 2; ++mt)
            #pragma unroll
            for (int nt = 0; nt < 4; ++nt) {
                acc[mt][nt] = MFMA16(afh[mt], bfh[nt], acc[mt][nt]);
                acc[mt][nt] = MFMA16(afh[mt], bfl[nt], acc[mt][nt]);
                acc[mt][nt] = MFMA16(afl[mt], bfh[nt], acc[mt][nt]);
            }
        __syncthreads();
    }

    #pragma unroll
    for (int nt = 0; nt < 4; ++nt) {
        const int ng = n0 + wn * 64 + nt * 16 + l16;
        const float bias = ob[ng];
        #pragma unroll
        for (int mt = 0; mt < 2; ++mt) {
            const int m = m0 + wm * 32 + mt * 16 + quad * 4;
            #pragma unroll
            for (int r = 0; r < 4; ++r)
                out[(size_t)(m + r) * Wn + ng] = acc[mt][nt][r] + bias;
        }
    }
}

// ---------------------------------------------------------------------------
extern "C" void kernel_launch(void* const* d_in, const int* in_sizes, int n_in,
                              void* d_out, int out_size, void* d_ws, size_t ws_size,
                              hipStream_t stream) {
    const float* x    = (const float*)d_in[0];
    const int*   mask = (const int*)  d_in[1];
    const float* qw = (const float*)d_in[2];
    const float* qb = (const float*)d_in[3];
    const float* kw = (const float*)d_in[4];
    const float* kb = (const float*)d_in[5];
    const float* vw = (const float*)d_in[6];
    const float* vb = (const float*)d_in[7];
    const float* ow = (const float*)d_in[8];
    const float* ob = (const float*)d_in[9];

    float* out  = (float*)d_out;                       // [4096, 768]
    float* attn = out + XE;                            // [B,H,S,S]

    char* w = (char*)d_ws;
    unsigned short* xh   = (unsigned short*)w;  w += XE * 2;     // also aoh
    unsigned short* xl   = (unsigned short*)w;  w += XE * 2;     // also aol
    unsigned short* wqh  = (unsigned short*)w;  w += (size_t)3 * Wn * Wn * 2;
    unsigned short* wql  = (unsigned short*)w;  w += (size_t)3 * Wn * Wn * 2;
    unsigned short* woh  = (unsigned short*)w;  w += (size_t)Wn * Wn * 2;
    unsigned short* wol  = (unsigned short*)w;  w += (size_t)Wn * Wn * 2;
    float*          bq   = (float*)w;           w += (size_t)3 * Wn * 4;
    unsigned short* qh   = (unsigned short*)w;  w += XE * 2;
    unsigned short* kh   = (unsigned short*)w;  w += XE * 2;
    unsigned short* vt_w = (unsigned short*)w;  w += XE * 2;
    float*          lpart = (float*)w;          w += (size_t)4 * Bn * Hn * Sn * 4;

    prep_kernel<<<5385, 256, 0, stream>>>(x, qw, kw, vw, ow, qb, kb, vb,
                                          xh, xl, wqh, wql, woh, wol, bq);

    qkv_mfma_kernel<<<dim3(32, 18), 256, 0, stream>>>(
        xh, xl, wqh, wql, bq, qh, kh, vt_w);

    attn_sum_kernel<<<dim3(64, Hn, Bn), 256, 0, stream>>>(
        qh, kh, mask, lpart);

    attn_out_kernel<<<dim3(16, Hn, Bn), 256, 0, stream>>>(
        qh, kh, vt_w, mask, lpart, attn, xh, xl);

    oproj_mfma_kernel<<<dim3(64, 6), 256, 0, stream>>>(
        xh, xl, woh, wol, ob, out);
}

// Round 3
// 444.937 us; speedup vs baseline: 1.0394x; 1.0394x over previous
//
#include <hip/hip_runtime.h>

#define Bn 4
#define Sn 1024
#define En 1024
#define Wn 768
#define Hn 12
#define Dn 64
#define XE ((size_t)Bn * Sn * Wn)   // 3,145,728

typedef __attribute__((ext_vector_type(8))) short short8;
typedef __attribute__((ext_vector_type(4))) short short4v;
typedef __attribute__((ext_vector_type(4))) float floatx4;

#define MFMA16(A, B, C) __builtin_amdgcn_mfma_f32_16x16x32_bf16(A, B, C, 0, 0, 0)

__device__ __forceinline__ unsigned short f2bf_rn(float f) {
    unsigned int u = __float_as_uint(f);
    unsigned int r = u + 0x7fffu + ((u >> 16) & 1u);
    return (unsigned short)(r >> 16);
}
__device__ __forceinline__ float bf2f(unsigned short h) {
    return __uint_as_float(((unsigned int)h) << 16);
}

__device__ __forceinline__ void gload_lds16(const unsigned short* g, unsigned short* l) {
    __builtin_amdgcn_global_load_lds(
        (const __attribute__((address_space(1))) void*)g,
        (__attribute__((address_space(3))) void*)l, 16, 0, 0);
}

// ---------------------------------------------------------------------------
// Fused prep: x split (3072 blocks) + 3 qkv-weight splits (1728) +
// o-weight split (576) + bias concat (9).
// ---------------------------------------------------------------------------
__global__ __launch_bounds__(256) void prep_kernel(
    const float* __restrict__ x,
    const float* __restrict__ qw, const float* __restrict__ kw,
    const float* __restrict__ vw, const float* __restrict__ ow,
    const float* __restrict__ qb, const float* __restrict__ kb,
    const float* __restrict__ vb,
    unsigned short* __restrict__ xh, unsigned short* __restrict__ xl,
    unsigned short* __restrict__ wqh, unsigned short* __restrict__ wql,
    unsigned short* __restrict__ woh, unsigned short* __restrict__ wol,
    float* __restrict__ bq)
{
    const int bx = blockIdx.x;
    const float* src; unsigned short *dh, *dl; int e;
    if (bx < 3072) {
        e = (bx * 256 + threadIdx.x) * 4;
        src = x; dh = xh; dl = xl;
    } else if (bx < 3072 + 1728) {
        int bb = bx - 3072; int which = bb / 576;
        e = ((bb - which * 576) * 256 + threadIdx.x) * 4;
        src = (which == 0) ? qw : (which == 1) ? kw : vw;
        dh = wqh + (size_t)which * Wn * Wn;
        dl = wql + (size_t)which * Wn * Wn;
    } else if (bx < 3072 + 1728 + 576) {
        e = ((bx - 3072 - 1728) * 256 + threadIdx.x) * 4;
        src = ow; dh = woh; dl = wol;
    } else {
        int t = (bx - 3072 - 1728 - 576) * 256 + threadIdx.x;
        if (t < Wn) bq[t] = qb[t];
        else if (t < 2 * Wn) bq[t] = kb[t - Wn];
        else if (t < 3 * Wn) bq[t] = vb[t - 2 * Wn];
        return;
    }
    int row = e / Wn, col = e - row * Wn;
    float4 v = *(const float4*)(src + (size_t)row * En + col);
    float f[4] = {v.x, v.y, v.z, v.w};
    short4v h, l;
    #pragma unroll
    for (int i = 0; i < 4; ++i) {
        unsigned short hh = f2bf_rn(f[i]);
        h[i] = (short)hh;
        l[i] = (short)f2bf_rn(f[i] - bf2f(hh));
    }
    *(short4v*)(dh + e) = h;
    *(short4v*)(dl + e) = l;
}

// ---------------------------------------------------------------------------
// QKV GEMM.  q/k: SINGLE-term bf16 (outputs are bf16-rounded anyway, the
// dropped cross terms are below output quantization).  v: bf16x3.
// q/k out: bf16 [B,H,S,D]; v out: bf16 [B,H,D,S].
// ---------------------------------------------------------------------------
__global__ __launch_bounds__(256) void qkv_mfma_kernel(
    const unsigned short* __restrict__ xh, const unsigned short* __restrict__ xl,
    const unsigned short* __restrict__ wh, const unsigned short* __restrict__ wl,
    const float* __restrict__ bq,
    unsigned short* __restrict__ qh_o, unsigned short* __restrict__ kh_o,
    unsigned short* __restrict__ vt_o)
{
    __shared__ __align__(16) unsigned short Ah[128 * 32];
    __shared__ __align__(16) unsigned short Al[128 * 32];
    __shared__ __align__(16) unsigned short Bh[128 * 32];
    __shared__ __align__(16) unsigned short Bl[128 * 32];

    const int tid = threadIdx.x;
    const int wave = tid >> 6, lane = tid & 63;
    const int quad = lane >> 4, l16 = lane & 15;
    const int m0 = blockIdx.x * 128, n0 = blockIdx.y * 128;
    const int wm = wave >> 1, wn = wave & 1;
    const int which = n0 / Wn;                 // 0=q 1=k 2=v (blocks never straddle)
    const bool full = (which == 2);

    floatx4 acc[4][4] = {};

    const unsigned short* gsrc = (wave == 0) ? xh : (wave == 1) ? xl
                               : (wave == 2) ? wh : wl;
    unsigned short* ldst = (wave == 0) ? Ah : (wave == 1) ? Al
                         : (wave == 2) ? Bh : Bl;
    const int base_row = (wave < 2) ? m0 : n0;
    const int r_in = lane >> 2;
    const int cs = (lane & 3) ^ (r_in & 3);

    for (int k0 = 0; k0 < Wn; k0 += 32) {
        if (full || wave == 0 || wave == 2) {  // Al/Bl only needed for v-blocks
            #pragma unroll
            for (int i = 0; i < 8; ++i) {
                int r = i * 16 + r_in;
                const unsigned short* gp =
                    gsrc + (size_t)(base_row + r) * Wn + k0 + cs * 8;
                gload_lds16(gp, ldst + i * 512);
            }
        }
        __syncthreads();

        short8 afh[4], afl[4], bfh[4], bfl[4];
        #pragma unroll
        for (int t = 0; t < 4; ++t) {
            int mr = wm * 64 + t * 16 + l16;
            int ca = quad ^ (mr & 3);
            afh[t] = *(const short8*)(Ah + mr * 32 + ca * 8);
            if (full) afl[t] = *(const short8*)(Al + mr * 32 + ca * 8);
            int nr = wn * 64 + t * 16 + l16;
            int cb = quad ^ (nr & 3);
            bfh[t] = *(const short8*)(Bh + nr * 32 + cb * 8);
            if (full) bfl[t] = *(const short8*)(Bl + nr * 32 + cb * 8);
        }
        #pragma unroll
        for (int mt = 0; mt < 4; ++mt)
            #pragma unroll
            for (int nt = 0; nt < 4; ++nt) {
                acc[mt][nt] = MFMA16(afh[mt], bfh[nt], acc[mt][nt]);
                if (full) {
                    acc[mt][nt] = MFMA16(afh[mt], bfl[nt], acc[mt][nt]);
                    acc[mt][nt] = MFMA16(afl[mt], bfh[nt], acc[mt][nt]);
                }
            }
        __syncthreads();
    }

    const int b = m0 >> 10;
    #pragma unroll
    for (int nt = 0; nt < 4; ++nt) {
        const int ng = n0 + wn * 64 + nt * 16 + l16;
        const float bias = bq[ng];
        const int f = ng - which * Wn;
        const int h = f >> 6, d = f & 63;
        #pragma unroll
        for (int mt = 0; mt < 4; ++mt) {
            const int mbase = m0 + wm * 64 + mt * 16 + quad * 4;
            const int s0 = mbase & (Sn - 1);
            if (which < 2) {
                unsigned short* oq = which ? kh_o : qh_o;
                size_t idx = (((size_t)(b * Hn + h)) * Sn + s0) * Dn + d;
                #pragma unroll
                for (int r = 0; r < 4; ++r)
                    oq[idx + (size_t)r * Dn] = f2bf_rn(acc[mt][nt][r] + bias);
            } else {
                size_t idx = (((size_t)(b * Hn + h)) * Dn + d) * Sn + s0;
                short4v pk;
                #pragma unroll
                for (int r = 0; r < 4; ++r)
                    pk[r] = (short)f2bf_rn(acc[mt][nt][r] + bias);
                *(short4v*)(vt_o + idx) = pk;
            }
        }
    }
}

// ---------------------------------------------------------------------------
// Attention pass A: partial softmax denominators over a 256-key range.
// bf16 Q/K fragments loaded per-lane straight from global; mask in LDS.
// grid.x = qt*4 + ks (64), y=h, z=b -> 3072 blocks.
// ---------------------------------------------------------------------------
__global__ __launch_bounds__(256) void attn_sum_kernel(
    const unsigned short* __restrict__ qh, const unsigned short* __restrict__ kh,
    const int* __restrict__ mask, float* __restrict__ lpart)
{
    __shared__ float msk[256];

    const int tid = threadIdx.x;
    const int wave = tid >> 6, lane = tid & 63;
    const int quad = lane >> 4, l16 = lane & 15;
    const int qt = blockIdx.x >> 2, ks = blockIdx.x & 3;
    const int h = blockIdx.y, b = blockIdx.z;
    const int bh = b * Hn + h;
    const size_t kvb = (size_t)bh * Sn * Dn;

    if (tid < 64) {
        int4 mi = *(const int4*)(mask + b * Sn + ks * 256 + tid * 4);
        msk[tid * 4 + 0] = (float)mi.x;
        msk[tid * 4 + 1] = (float)mi.y;
        msk[tid * 4 + 2] = (float)mi.z;
        msk[tid * 4 + 3] = (float)mi.w;
    }

    short8 qf[2];
    {
        const int s = qt * 64 + wave * 16 + l16;
        const unsigned short* qp = qh + kvb + (size_t)s * Dn + quad * 8;
        qf[0] = *(const short8*)(qp);
        qf[1] = *(const short8*)(qp + 32);
    }
    __syncthreads();

    float lsum[4] = {0.f, 0.f, 0.f, 0.f};

    for (int kt = 0; kt < 4; ++kt) {
        #pragma unroll
        for (int ct = 0; ct < 4; ++ct) {
            const int kl = kt * 64 + ct * 16 + l16;
            const unsigned short* kp = kh + kvb + (size_t)(ks * 256 + kl) * Dn + quad * 8;
            short8 kf0 = *(const short8*)(kp);
            short8 kf1 = *(const short8*)(kp + 32);
            floatx4 acc = {0.f, 0.f, 0.f, 0.f};
            acc = MFMA16(qf[0], kf0, acc);
            acc = MFMA16(qf[1], kf1, acc);
            const float mv = msk[kl];
            #pragma unroll
            for (int r = 0; r < 4; ++r)
                lsum[r] += __expf(acc[r] * 0.125f) * mv;
        }
    }

    #pragma unroll
    for (int r = 0; r < 4; ++r) {
        float v = lsum[r];
        v += __shfl_xor(v, 1, 64);
        v += __shfl_xor(v, 2, 64);
        v += __shfl_xor(v, 4, 64);
        v += __shfl_xor(v, 8, 64);
        lsum[r] = v;
    }
    if (l16 == 0) {
        const int row = qt * 64 + wave * 16 + quad * 4;
        #pragma unroll
        for (int r = 0; r < 4; ++r)
            lpart[((size_t)ks * Bn * Hn + bh) * Sn + row + r] = lsum[r];
    }
}

// ---------------------------------------------------------------------------
// Attention pass B: recompute scores over ALL keys, write fp32 weights from
// the Ps-transposed bf16 fragments (coalesced dwordx4), accumulate full O in
// registers, emit bf16 hi/lo AO directly.  grid (16, H, B) = 768 blocks.
// ---------------------------------------------------------------------------
__global__ __launch_bounds__(256) void attn_out_kernel(
    const unsigned short* __restrict__ qh, const unsigned short* __restrict__ kh,
    const unsigned short* __restrict__ vt, const int* __restrict__ mask,
    const float* __restrict__ lpart, float* __restrict__ attn,
    unsigned short* __restrict__ aoh, unsigned short* __restrict__ aol)
{
    __shared__ __align__(16) unsigned short Ps[4][16 * 72];
    __shared__ float msk[Sn];

    const int tid = threadIdx.x;
    const int wave = tid >> 6, lane = tid & 63;
    const int quad = lane >> 4, l16 = lane & 15;
    const int qt = blockIdx.x;
    const int h = blockIdx.y, b = blockIdx.z;
    const int bh = b * Hn + h;
    const size_t kvb = (size_t)bh * Sn * Dn;
    const size_t vbase = (size_t)bh * Dn * Sn;

    {
        int4 mi = *(const int4*)(mask + b * Sn + tid * 4);
        msk[tid * 4 + 0] = (float)mi.x;
        msk[tid * 4 + 1] = (float)mi.y;
        msk[tid * 4 + 2] = (float)mi.z;
        msk[tid * 4 + 3] = (float)mi.w;
    }

    short8 qf[2];
    {
        const int s = qt * 64 + wave * 16 + l16;
        const unsigned short* qp = qh + kvb + (size_t)s * Dn + quad * 8;
        qf[0] = *(const short8*)(qp);
        qf[1] = *(const short8*)(qp + 32);
    }

    const int row0 = qt * 64 + wave * 16 + quad * 4;
    float li[4];
    #pragma unroll
    for (int r = 0; r < 4; ++r) {
        float lv = 0.f;
        #pragma unroll
        for (int s4 = 0; s4 < 4; ++s4)
            lv += lpart[((size_t)s4 * Bn * Hn + bh) * Sn + row0 + r];
        li[r] = (lv > 0.f) ? 1.f / lv : 0.f;
    }
    __syncthreads();

    floatx4 oacc[4] = {};
    float* aprow = attn + ((size_t)bh * Sn + qt * 64 + wave * 16 + l16) * Sn;

    for (int kk = 0; kk < 16; ++kk) {
        const int k0 = kk * 64;
        #pragma unroll
        for (int ct = 0; ct < 4; ++ct) {
            const int key = k0 + ct * 16 + l16;
            const unsigned short* kp = kh + kvb + (size_t)key * Dn + quad * 8;
            short8 kf0 = *(const short8*)(kp);
            short8 kf1 = *(const short8*)(kp + 32);
            floatx4 acc = {0.f, 0.f, 0.f, 0.f};
            acc = MFMA16(qf[0], kf0, acc);
            acc = MFMA16(qf[1], kf1, acc);
            const float mv = msk[key];
            #pragma unroll
            for (int r = 0; r < 4; ++r) {
                const float p = __expf(acc[r] * 0.125f) * mv * li[r];
                Ps[wave][(quad * 4 + r) * 72 + ct * 16 + l16] = f2bf_rn(p);
            }
        }
        // Read back wave-local Ps fragment once: feeds BOTH the coalesced
        // fp32 attn store and the PV MFMA.  (in-wave LDS ordering)
        #pragma unroll
        for (int ksp = 0; ksp < 2; ++ksp) {
            short8 pf = *(const short8*)&Ps[wave][l16 * 72 + ksp * 32 + quad * 8];
            float4 f0, f1;
            f0.x = bf2f((unsigned short)pf[0]); f0.y = bf2f((unsigned short)pf[1]);
            f0.z = bf2f((unsigned short)pf[2]); f0.w = bf2f((unsigned short)pf[3]);
            f1.x = bf2f((unsigned short)pf[4]); f1.y = bf2f((unsigned short)pf[5]);
            f1.z = bf2f((unsigned short)pf[6]); f1.w = bf2f((unsigned short)pf[7]);
            float* ap = aprow + k0 + ksp * 32 + quad * 8;
            *(float4*)(ap)     = f0;
            *(float4*)(ap + 4) = f1;
            #pragma unroll
            for (int dt = 0; dt < 4; ++dt) {
                short8 vf = *(const short8*)(vt + vbase
                              + (size_t)(dt * 16 + l16) * Sn + k0 + ksp * 32 + quad * 8);
                oacc[dt] = MFMA16(pf, vf, oacc[dt]);
            }
        }
    }

    #pragma unroll
    for (int dt = 0; dt < 4; ++dt) {
        #pragma unroll
        for (int r = 0; r < 4; ++r) {
            const float o = oacc[dt][r];
            const unsigned short hh = f2bf_rn(o);
            const size_t idx = ((size_t)b * Sn + row0 + r) * Wn + h * Dn + dt * 16 + l16;
            aoh[idx] = hh;
            aol[idx] = f2bf_rn(o - bf2f(hh));
        }
    }
}

// ---------------------------------------------------------------------------
// O projection: 64x128 tiles -> grid (64,6) = 384 blocks.
// ---------------------------------------------------------------------------
__global__ __launch_bounds__(256) void oproj_mfma_kernel(
    const unsigned short* __restrict__ aoh, const unsigned short* __restrict__ aol,
    const unsigned short* __restrict__ wh, const unsigned short* __restrict__ wl,
    const float* __restrict__ ob, float* __restrict__ out)
{
    __shared__ __align__(16) unsigned short Ah[64 * 32];
    __shared__ __align__(16) unsigned short Al[64 * 32];
    __shared__ __align__(16) unsigned short Bh[128 * 32];
    __shared__ __align__(16) unsigned short Bl[128 * 32];

    const int tid = threadIdx.x;
    const int wave = tid >> 6, lane = tid & 63;
    const int quad = lane >> 4, l16 = lane & 15;
    const int m0 = blockIdx.x * 64, n0 = blockIdx.y * 128;
    const int wm = wave >> 1, wn = wave & 1;

    floatx4 acc[2][4] = {};

    const int r_in = lane >> 2;
    const int cs = (lane & 3) ^ (r_in & 3);

    for (int k0 = 0; k0 < Wn; k0 += 32) {
        if (wave == 0) {
            #pragma unroll
            for (int i = 0; i < 4; ++i) {
                gload_lds16(aoh + (size_t)(m0 + i * 16 + r_in) * Wn + k0 + cs * 8,
                            Ah + i * 512);
                gload_lds16(aol + (size_t)(m0 + i * 16 + r_in) * Wn + k0 + cs * 8,
                            Al + i * 512);
            }
        } else if (wave == 1) {
            #pragma unroll
            for (int i = 0; i < 8; ++i)
                gload_lds16(wh + (size_t)(n0 + i * 16 + r_in) * Wn + k0 + cs * 8,
                            Bh + i * 512);
        } else if (wave == 2) {
            #pragma unroll
            for (int i = 0; i < 8; ++i)
                gload_lds16(wl + (size_t)(n0 + i * 16 + r_in) * Wn + k0 + cs * 8,
                            Bl + i * 512);
        }
        __syncthreads();

        short8 afh[2], afl[2], bfh[4], bfl[4];
        #pragma unroll
        for (int t = 0; t < 2; ++t) {
            int mr = wm * 32 + t * 16 + l16;
            int ca = quad ^ (mr & 3);
            afh[t] = *(const short8*)(Ah + mr * 32 + ca * 8);
            afl[t] = *(const short8*)(Al + mr * 32 + ca * 8);
        }
        #pragma unroll
        for (int t = 0; t < 4; ++t) {
            int nr = wn * 64 + t * 16 + l16;
            int cb = quad ^ (nr & 3);
            bfh[t] = *(const short8*)(Bh + nr * 32 + cb * 8);
            bfl[t] = *(const short8*)(Bl + nr * 32 + cb * 8);
        }
        #pragma unroll
        for (int mt = 0; mt < 2; ++mt)
            #pragma unroll
            for (int nt = 0; nt < 4; ++nt) {
                acc[mt][nt] = MFMA16(afh[mt], bfh[nt], acc[mt][nt]);
                acc[mt][nt] = MFMA16(afh[mt], bfl[nt], acc[mt][nt]);
                acc[mt][nt] = MFMA16(afl[mt], bfh[nt], acc[mt][nt]);
            }
        __syncthreads();
    }

    #pragma unroll
    for (int nt = 0; nt < 4; ++nt) {
        const int ng = n0 + wn * 64 + nt * 16 + l16;
        const float bias = ob[ng];
        #pragma unroll
        for (int mt = 0; mt < 2; ++mt) {
            const int m = m0 + wm * 32 + mt * 16 + quad * 4;
            #pragma unroll
            for (int r = 0; r < 4; ++r)
                out[(size_t)(m + r) * Wn + ng] = acc[mt][nt][r] + bias;
        }
    }
}

// ---------------------------------------------------------------------------
extern "C" void kernel_launch(void* const* d_in, const int* in_sizes, int n_in,
                              void* d_out, int out_size, void* d_ws, size_t ws_size,
                              hipStream_t stream) {
    const float* x    = (const float*)d_in[0];
    const int*   mask = (const int*)  d_in[1];
    const float* qw = (const float*)d_in[2];
    const float* qb = (const float*)d_in[3];
    const float* kw = (const float*)d_in[4];
    const float* kb = (const float*)d_in[5];
    const float* vw = (const float*)d_in[6];
    const float* vb = (const float*)d_in[7];
    const float* ow = (const float*)d_in[8];
    const float* ob = (const float*)d_in[9];

    float* out  = (float*)d_out;                       // [4096, 768]
    float* attn = out + XE;                            // [B,H,S,S]

    char* w = (char*)d_ws;
    unsigned short* xh   = (unsigned short*)w;  w += XE * 2;     // also aoh
    unsigned short* xl   = (unsigned short*)w;  w += XE * 2;     // also aol
    unsigned short* wqh  = (unsigned short*)w;  w += (size_t)3 * Wn * Wn * 2;
    unsigned short* wql  = (unsigned short*)w;  w += (size_t)3 * Wn * Wn * 2;
    unsigned short* woh  = (unsigned short*)w;  w += (size_t)Wn * Wn * 2;
    unsigned short* wol  = (unsigned short*)w;  w += (size_t)Wn * Wn * 2;
    float*          bq   = (float*)w;           w += (size_t)3 * Wn * 4;
    unsigned short* qh   = (unsigned short*)w;  w += XE * 2;
    unsigned short* kh   = (unsigned short*)w;  w += XE * 2;
    unsigned short* vt_w = (unsigned short*)w;  w += XE * 2;
    float*          lpart = (float*)w;          w += (size_t)4 * Bn * Hn * Sn * 4;

    prep_kernel<<<5385, 256, 0, stream>>>(x, qw, kw, vw, ow, qb, kb, vb,
                                          xh, xl, wqh, wql, woh, wol, bq);

    qkv_mfma_kernel<<<dim3(32, 18), 256, 0, stream>>>(
        xh, xl, wqh, wql, bq, qh, kh, vt_w);

    attn_sum_kernel<<<dim3(64, Hn, Bn), 256, 0, stream>>>(
        qh, kh, mask, lpart);

    attn_out_kernel<<<dim3(16, Hn, Bn), 256, 0, stream>>>(
        qh, kh, vt_w, mask, lpart, attn, xh, xl);

    oproj_mfma_kernel<<<dim3(64, 6), 256, 0, stream>>>(
        xh, xl, woh, wol, ob, out);
}

// Round 4
// 408.222 us; speedup vs baseline: 1.1329x; 1.0899x over previous
//
#include <hip/hip_runtime.h>

#define Bn 4
#define Sn 1024
#define En 1024
#define Wn 768
#define Hn 12
#define Dn 64
#define XE ((size_t)Bn * Sn * Wn)   // 3,145,728

typedef __attribute__((ext_vector_type(8))) short short8;
typedef __attribute__((ext_vector_type(4))) short short4v;
typedef __attribute__((ext_vector_type(4))) float floatx4;

#define MFMA16(A, B, C) __builtin_amdgcn_mfma_f32_16x16x32_bf16(A, B, C, 0, 0, 0)

__device__ __forceinline__ unsigned short f2bf_rn(float f) {
    unsigned int u = __float_as_uint(f);
    unsigned int r = u + 0x7fffu + ((u >> 16) & 1u);
    return (unsigned short)(r >> 16);
}
__device__ __forceinline__ float bf2f(unsigned short h) {
    return __uint_as_float(((unsigned int)h) << 16);
}

__device__ __forceinline__ void gload_lds16(const unsigned short* g, unsigned short* l) {
    __builtin_amdgcn_global_load_lds(
        (const __attribute__((address_space(1))) void*)g,
        (__attribute__((address_space(3))) void*)l, 16, 0, 0);
}

// ---------------------------------------------------------------------------
// Fused prep: x split (3072 blocks) + 3 qkv-weight splits (1728) +
// o-weight split (576) + bias concat (9).
// ---------------------------------------------------------------------------
__global__ __launch_bounds__(256) void prep_kernel(
    const float* __restrict__ x,
    const float* __restrict__ qw, const float* __restrict__ kw,
    const float* __restrict__ vw, const float* __restrict__ ow,
    const float* __restrict__ qb, const float* __restrict__ kb,
    const float* __restrict__ vb,
    unsigned short* __restrict__ xh, unsigned short* __restrict__ xl,
    unsigned short* __restrict__ wqh, unsigned short* __restrict__ wql,
    unsigned short* __restrict__ woh, unsigned short* __restrict__ wol,
    float* __restrict__ bq)
{
    const int bx = blockIdx.x;
    const float* src; unsigned short *dh, *dl; int e;
    if (bx < 3072) {
        e = (bx * 256 + threadIdx.x) * 4;
        src = x; dh = xh; dl = xl;
    } else if (bx < 3072 + 1728) {
        int bb = bx - 3072; int which = bb / 576;
        e = ((bb - which * 576) * 256 + threadIdx.x) * 4;
        src = (which == 0) ? qw : (which == 1) ? kw : vw;
        dh = wqh + (size_t)which * Wn * Wn;
        dl = wql + (size_t)which * Wn * Wn;
    } else if (bx < 3072 + 1728 + 576) {
        e = ((bx - 3072 - 1728) * 256 + threadIdx.x) * 4;
        src = ow; dh = woh; dl = wol;
    } else {
        int t = (bx - 3072 - 1728 - 576) * 256 + threadIdx.x;
        if (t < Wn) bq[t] = qb[t];
        else if (t < 2 * Wn) bq[t] = kb[t - Wn];
        else if (t < 3 * Wn) bq[t] = vb[t - 2 * Wn];
        return;
    }
    int row = e / Wn, col = e - row * Wn;
    float4 v = *(const float4*)(src + (size_t)row * En + col);
    float f[4] = {v.x, v.y, v.z, v.w};
    short4v h, l;
    #pragma unroll
    for (int i = 0; i < 4; ++i) {
        unsigned short hh = f2bf_rn(f[i]);
        h[i] = (short)hh;
        l[i] = (short)f2bf_rn(f[i] - bf2f(hh));
    }
    *(short4v*)(dh + e) = h;
    *(short4v*)(dl + e) = l;
}

// ---------------------------------------------------------------------------
// QKV GEMM.  q/k: SINGLE-term bf16 (outputs are bf16-rounded anyway, the
// dropped cross terms are below output quantization).  v: bf16x3.
// q/k out: bf16 [B,H,S,D]; v out: bf16 [B,H,D,S].
// ---------------------------------------------------------------------------
__global__ __launch_bounds__(256) void qkv_mfma_kernel(
    const unsigned short* __restrict__ xh, const unsigned short* __restrict__ xl,
    const unsigned short* __restrict__ wh, const unsigned short* __restrict__ wl,
    const float* __restrict__ bq,
    unsigned short* __restrict__ qh_o, unsigned short* __restrict__ kh_o,
    unsigned short* __restrict__ vt_o)
{
    __shared__ __align__(16) unsigned short Ah[128 * 32];
    __shared__ __align__(16) unsigned short Al[128 * 32];
    __shared__ __align__(16) unsigned short Bh[128 * 32];
    __shared__ __align__(16) unsigned short Bl[128 * 32];

    const int tid = threadIdx.x;
    const int wave = tid >> 6, lane = tid & 63;
    const int quad = lane >> 4, l16 = lane & 15;
    const int m0 = blockIdx.x * 128, n0 = blockIdx.y * 128;
    const int wm = wave >> 1, wn = wave & 1;
    const int which = n0 / Wn;                 // 0=q 1=k 2=v (blocks never straddle)
    const bool full = (which == 2);

    floatx4 acc[4][4] = {};

    const unsigned short* gsrc = (wave == 0) ? xh : (wave == 1) ? xl
                               : (wave == 2) ? wh : wl;
    unsigned short* ldst = (wave == 0) ? Ah : (wave == 1) ? Al
                         : (wave == 2) ? Bh : Bl;
    const int base_row = (wave < 2) ? m0 : n0;
    const int r_in = lane >> 2;
    const int cs = (lane & 3) ^ (r_in & 3);

    for (int k0 = 0; k0 < Wn; k0 += 32) {
        if (full || wave == 0 || wave == 2) {  // Al/Bl only needed for v-blocks
            #pragma unroll
            for (int i = 0; i < 8; ++i) {
                int r = i * 16 + r_in;
                const unsigned short* gp =
                    gsrc + (size_t)(base_row + r) * Wn + k0 + cs * 8;
                gload_lds16(gp, ldst + i * 512);
            }
        }
        __syncthreads();

        short8 afh[4], afl[4], bfh[4], bfl[4];
        #pragma unroll
        for (int t = 0; t < 4; ++t) {
            int mr = wm * 64 + t * 16 + l16;
            int ca = quad ^ (mr & 3);
            afh[t] = *(const short8*)(Ah + mr * 32 + ca * 8);
            if (full) afl[t] = *(const short8*)(Al + mr * 32 + ca * 8);
            int nr = wn * 64 + t * 16 + l16;
            int cb = quad ^ (nr & 3);
            bfh[t] = *(const short8*)(Bh + nr * 32 + cb * 8);
            if (full) bfl[t] = *(const short8*)(Bl + nr * 32 + cb * 8);
        }
        #pragma unroll
        for (int mt = 0; mt < 4; ++mt)
            #pragma unroll
            for (int nt = 0; nt < 4; ++nt) {
                acc[mt][nt] = MFMA16(afh[mt], bfh[nt], acc[mt][nt]);
                if (full) {
                    acc[mt][nt] = MFMA16(afh[mt], bfl[nt], acc[mt][nt]);
                    acc[mt][nt] = MFMA16(afl[mt], bfh[nt], acc[mt][nt]);
                }
            }
        __syncthreads();
    }

    const int b = m0 >> 10;
    #pragma unroll
    for (int nt = 0; nt < 4; ++nt) {
        const int ng = n0 + wn * 64 + nt * 16 + l16;
        const float bias = bq[ng];
        const int f = ng - which * Wn;
        const int h = f >> 6, d = f & 63;
        #pragma unroll
        for (int mt = 0; mt < 4; ++mt) {
            const int mbase = m0 + wm * 64 + mt * 16 + quad * 4;
            const int s0 = mbase & (Sn - 1);
            if (which < 2) {
                unsigned short* oq = which ? kh_o : qh_o;
                size_t idx = (((size_t)(b * Hn + h)) * Sn + s0) * Dn + d;
                #pragma unroll
                for (int r = 0; r < 4; ++r)
                    oq[idx + (size_t)r * Dn] = f2bf_rn(acc[mt][nt][r] + bias);
            } else {
                size_t idx = (((size_t)(b * Hn + h)) * Dn + d) * Sn + s0;
                short4v pk;
                #pragma unroll
                for (int r = 0; r < 4; ++r)
                    pk[r] = (short)f2bf_rn(acc[mt][nt][r] + bias);
                *(short4v*)(vt_o + idx) = pk;
            }
        }
    }
}

// ---------------------------------------------------------------------------
// Fused attention: ONE pass.  8 waves/block; wave-pair owns 16 q-rows, each
// wave one 512-key half.  Phase 1: QK^T + exp once, transposed P fragments
// persisted in registers (short8 Pr[16], static indexing), row-sum l
// accumulated.  Cross-pair l via LDS.  Phase 2: coalesced fp32 attn stores
// (normalized) + PV MFMA (unnormalized P, O scaled by 1/l at the end).
// grid (16, H, B) = 768 blocks x 512 threads.
// ---------------------------------------------------------------------------
__global__ __launch_bounds__(512) void attn_fused_kernel(
    const unsigned short* __restrict__ qh, const unsigned short* __restrict__ kh,
    const unsigned short* __restrict__ vt, const int* __restrict__ mask,
    float* __restrict__ attn,
    unsigned short* __restrict__ aoh, unsigned short* __restrict__ aol)
{
    __shared__ __align__(16) unsigned short Ps[8][16 * 72];
    __shared__ float msk[Sn];
    __shared__ float Lsum[8][16];
    __shared__ __align__(16) float Obuf[4][16][68];   // padded: no 4-way bank alias

    const int tid = threadIdx.x;
    const int wave = tid >> 6, lane = tid & 63;
    const int quad = lane >> 4, l16 = lane & 15;
    const int pair = wave >> 1, hf = wave & 1;
    const int qt = blockIdx.x;
    const int h = blockIdx.y, b = blockIdx.z;
    const int bh = b * Hn + h;
    const size_t kvb = (size_t)bh * Sn * Dn;
    const size_t vbase = (size_t)bh * Dn * Sn;

    if (tid < 256) {
        int4 mi = *(const int4*)(mask + b * Sn + tid * 4);
        msk[tid * 4 + 0] = (float)mi.x;
        msk[tid * 4 + 1] = (float)mi.y;
        msk[tid * 4 + 2] = (float)mi.z;
        msk[tid * 4 + 3] = (float)mi.w;
    }

    const int qrow = qt * 64 + pair * 16 + l16;
    short8 qf[2];
    {
        const unsigned short* qp = qh + kvb + (size_t)qrow * Dn + quad * 8;
        qf[0] = *(const short8*)(qp);
        qf[1] = *(const short8*)(qp + 32);
    }
    __syncthreads();                                   // msk ready

    // ---- Phase 1: scores + exp once; persist transposed P in registers ----
    short8 Pr[16];                                     // [kk*2+ksp], static idx
    float lsumr[4] = {0.f, 0.f, 0.f, 0.f};
    const int kbase = hf * 512;

    #pragma unroll
    for (int kk = 0; kk < 8; ++kk) {
        const int k0 = kbase + kk * 64;
        #pragma unroll
        for (int ct = 0; ct < 4; ++ct) {
            const int key = k0 + ct * 16 + l16;
            const unsigned short* kp = kh + kvb + (size_t)key * Dn + quad * 8;
            short8 kf0 = *(const short8*)(kp);
            short8 kf1 = *(const short8*)(kp + 32);
            floatx4 acc = {0.f, 0.f, 0.f, 0.f};
            acc = MFMA16(qf[0], kf0, acc);
            acc = MFMA16(qf[1], kf1, acc);
            const float mv = msk[key];
            #pragma unroll
            for (int r = 0; r < 4; ++r) {
                const float e = __expf(acc[r] * 0.125f) * mv;
                lsumr[r] += e;
                Ps[wave][(quad * 4 + r) * 72 + ct * 16 + l16] = f2bf_rn(e);
            }
        }
        // transpose readback (wave-local LDS; in-wave ordering)
        Pr[kk * 2 + 0] = *(const short8*)&Ps[wave][l16 * 72 + quad * 8];
        Pr[kk * 2 + 1] = *(const short8*)&Ps[wave][l16 * 72 + 32 + quad * 8];
    }

    // ---- denominator: intra-wave (over keys) then cross-pair via LDS ----
    #pragma unroll
    for (int r = 0; r < 4; ++r) {
        float v = lsumr[r];
        v += __shfl_xor(v, 1, 64);
        v += __shfl_xor(v, 2, 64);
        v += __shfl_xor(v, 4, 64);
        v += __shfl_xor(v, 8, 64);
        lsumr[r] = v;
    }
    if (l16 == 0) {
        #pragma unroll
        for (int r = 0; r < 4; ++r) Lsum[wave][quad * 4 + r] = lsumr[r];
    }
    __syncthreads();

    float li[4];
    #pragma unroll
    for (int r = 0; r < 4; ++r) {
        const float lv = Lsum[pair * 2][quad * 4 + r] + Lsum[pair * 2 + 1][quad * 4 + r];
        li[r] = (lv > 0.f) ? 1.f / lv : 0.f;
    }
    float lt;
    {
        const float lv = Lsum[pair * 2][l16] + Lsum[pair * 2 + 1][l16];
        lt = (lv > 0.f) ? 1.f / lv : 0.f;
    }

    // ---- Phase 2: attn stores (normalized) + PV from registers ----
    floatx4 oacc[4] = {};
    float* aprow = attn + ((size_t)bh * Sn + qrow) * Sn;

    #pragma unroll
    for (int kk = 0; kk < 8; ++kk) {
        const int k0 = kbase + kk * 64;
        #pragma unroll
        for (int ksp = 0; ksp < 2; ++ksp) {
            const short8 pf = Pr[kk * 2 + ksp];
            float4 f0, f1;
            f0.x = bf2f((unsigned short)pf[0]) * lt;
            f0.y = bf2f((unsigned short)pf[1]) * lt;
            f0.z = bf2f((unsigned short)pf[2]) * lt;
            f0.w = bf2f((unsigned short)pf[3]) * lt;
            f1.x = bf2f((unsigned short)pf[4]) * lt;
            f1.y = bf2f((unsigned short)pf[5]) * lt;
            f1.z = bf2f((unsigned short)pf[6]) * lt;
            f1.w = bf2f((unsigned short)pf[7]) * lt;
            float* ap = aprow + k0 + ksp * 32 + quad * 8;
            *(float4*)(ap)     = f0;
            *(float4*)(ap + 4) = f1;
            #pragma unroll
            for (int dt = 0; dt < 4; ++dt) {
                short8 vf = *(const short8*)(vt + vbase
                              + (size_t)(dt * 16 + l16) * Sn + k0 + ksp * 32 + quad * 8);
                oacc[dt] = MFMA16(pf, vf, oacc[dt]);   // unnormalized P
            }
        }
    }

    // ---- cross-pair O combine + epilogue (scale by 1/l once) ----
    if (hf == 1) {
        #pragma unroll
        for (int dt = 0; dt < 4; ++dt)
            #pragma unroll
            for (int r = 0; r < 4; ++r)
                Obuf[pair][quad * 4 + r][dt * 16 + l16] = oacc[dt][r];
    }
    __syncthreads();
    if (hf == 0) {
        const int row0 = qt * 64 + pair * 16 + quad * 4;
        #pragma unroll
        for (int dt = 0; dt < 4; ++dt)
            #pragma unroll
            for (int r = 0; r < 4; ++r) {
                const float o = (oacc[dt][r] + Obuf[pair][quad * 4 + r][dt * 16 + l16]) * li[r];
                const unsigned short hh = f2bf_rn(o);
                const size_t idx = ((size_t)b * Sn + row0 + r) * Wn + h * Dn + dt * 16 + l16;
                aoh[idx] = hh;
                aol[idx] = f2bf_rn(o - bf2f(hh));
            }
    }
}

// ---------------------------------------------------------------------------
// O projection: 64x128 tiles -> grid (64,6) = 384 blocks.
// ---------------------------------------------------------------------------
__global__ __launch_bounds__(256) void oproj_mfma_kernel(
    const unsigned short* __restrict__ aoh, const unsigned short* __restrict__ aol,
    const unsigned short* __restrict__ wh, const unsigned short* __restrict__ wl,
    const float* __restrict__ ob, float* __restrict__ out)
{
    __shared__ __align__(16) unsigned short Ah[64 * 32];
    __shared__ __align__(16) unsigned short Al[64 * 32];
    __shared__ __align__(16) unsigned short Bh[128 * 32];
    __shared__ __align__(16) unsigned short Bl[128 * 32];

    const int tid = threadIdx.x;
    const int wave = tid >> 6, lane = tid & 63;
    const int quad = lane >> 4, l16 = lane & 15;
    const int m0 = blockIdx.x * 64, n0 = blockIdx.y * 128;
    const int wm = wave >> 1, wn = wave & 1;

    floatx4 acc[2][4] = {};

    const int r_in = lane >> 2;
    const int cs = (lane & 3) ^ (r_in & 3);

    for (int k0 = 0; k0 < Wn; k0 += 32) {
        if (wave == 0) {
            #pragma unroll
            for (int i = 0; i < 4; ++i) {
                gload_lds16(aoh + (size_t)(m0 + i * 16 + r_in) * Wn + k0 + cs * 8,
                            Ah + i * 512);
                gload_lds16(aol + (size_t)(m0 + i * 16 + r_in) * Wn + k0 + cs * 8,
                            Al + i * 512);
            }
        } else if (wave == 1) {
            #pragma unroll
            for (int i = 0; i < 8; ++i)
                gload_lds16(wh + (size_t)(n0 + i * 16 + r_in) * Wn + k0 + cs * 8,
                            Bh + i * 512);
        } else if (wave == 2) {
            #pragma unroll
            for (int i = 0; i < 8; ++i)
                gload_lds16(wl + (size_t)(n0 + i * 16 + r_in) * Wn + k0 + cs * 8,
                            Bl + i * 512);
        }
        __syncthreads();

        short8 afh[2], afl[2], bfh[4], bfl[4];
        #pragma unroll
        for (int t = 0; t < 2; ++t) {
            int mr = wm * 32 + t * 16 + l16;
            int ca = quad ^ (mr & 3);
            afh[t] = *(const short8*)(Ah + mr * 32 + ca * 8);
            afl[t] = *(const short8*)(Al + mr * 32 + ca * 8);
        }
        #pragma unroll
        for (int t = 0; t < 4; ++t) {
            int nr = wn * 64 + t * 16 + l16;
            int cb = quad ^ (nr & 3);
            bfh[t] = *(const short8*)(Bh + nr * 32 + cb * 8);
            bfl[t] = *(const short8*)(Bl + nr * 32 + cb * 8);
        }
        #pragma unroll
        for (int mt = 0; mt < 2; ++mt)
            #pragma unroll
            for (int nt = 0; nt < 4; ++nt) {
                acc[mt][nt] = MFMA16(afh[mt], bfh[nt], acc[mt][nt]);
                acc[mt][nt] = MFMA16(afh[mt], bfl[nt], acc[mt][nt]);
                acc[mt][nt] = MFMA16(afl[mt], bfh[nt], acc[mt][nt]);
            }
        __syncthreads();
    }

    #pragma unroll
    for (int nt = 0; nt < 4; ++nt) {
        const int ng = n0 + wn * 64 + nt * 16 + l16;
        const float bias = ob[ng];
        #pragma unroll
        for (int mt = 0; mt < 2; ++mt) {
            const int m = m0 + wm * 32 + mt * 16 + quad * 4;
            #pragma unroll
            for (int r = 0; r < 4; ++r)
                out[(size_t)(m + r) * Wn + ng] = acc[mt][nt][r] + bias;
        }
    }
}

// ---------------------------------------------------------------------------
extern "C" void kernel_launch(void* const* d_in, const int* in_sizes, int n_in,
                              void* d_out, int out_size, void* d_ws, size_t ws_size,
                              hipStream_t stream) {
    const float* x    = (const float*)d_in[0];
    const int*   mask = (const int*)  d_in[1];
    const float* qw = (const float*)d_in[2];
    const float* qb = (const float*)d_in[3];
    const float* kw = (const float*)d_in[4];
    const float* kb = (const float*)d_in[5];
    const float* vw = (const float*)d_in[6];
    const float* vb = (const float*)d_in[7];
    const float* ow = (const float*)d_in[8];
    const float* ob = (const float*)d_in[9];

    float* out  = (float*)d_out;                       // [4096, 768]
    float* attn = out + XE;                            // [B,H,S,S]

    char* w = (char*)d_ws;
    unsigned short* xh   = (unsigned short*)w;  w += XE * 2;     // also aoh
    unsigned short* xl   = (unsigned short*)w;  w += XE * 2;     // also aol
    unsigned short* wqh  = (unsigned short*)w;  w += (size_t)3 * Wn * Wn * 2;
    unsigned short* wql  = (unsigned short*)w;  w += (size_t)3 * Wn * Wn * 2;
    unsigned short* woh  = (unsigned short*)w;  w += (size_t)Wn * Wn * 2;
    unsigned short* wol  = (unsigned short*)w;  w += (size_t)Wn * Wn * 2;
    float*          bq   = (float*)w;           w += (size_t)3 * Wn * 4;
    unsigned short* qh   = (unsigned short*)w;  w += XE * 2;
    unsigned short* kh   = (unsigned short*)w;  w += XE * 2;
    unsigned short* vt_w = (unsigned short*)w;  w += XE * 2;

    prep_kernel<<<5385, 256, 0, stream>>>(x, qw, kw, vw, ow, qb, kb, vb,
                                          xh, xl, wqh, wql, woh, wol, bq);

    qkv_mfma_kernel<<<dim3(32, 18), 256, 0, stream>>>(
        xh, xl, wqh, wql, bq, qh, kh, vt_w);

    attn_fused_kernel<<<dim3(16, Hn, Bn), 512, 0, stream>>>(
        qh, kh, vt_w, mask, attn, xh, xl);

    oproj_mfma_kernel<<<dim3(64, 6), 256, 0, stream>>>(
        xh, xl, woh, wol, ob, out);
}

// Round 5
// 390.831 us; speedup vs baseline: 1.1833x; 1.0445x over previous
//
#include <hip/hip_runtime.h>

#define Bn 4
#define Sn 1024
#define En 1024
#define Wn 768
#define Hn 12
#define Dn 64
#define XE ((size_t)Bn * Sn * Wn)   // 3,145,728

typedef __attribute__((ext_vector_type(8))) short short8;
typedef __attribute__((ext_vector_type(4))) short short4v;
typedef __attribute__((ext_vector_type(4))) float floatx4;

#define MFMA16(A, B, C) __builtin_amdgcn_mfma_f32_16x16x32_bf16(A, B, C, 0, 0, 0)

__device__ __forceinline__ unsigned short f2bf_rn(float f) {
    unsigned int u = __float_as_uint(f);
    unsigned int r = u + 0x7fffu + ((u >> 16) & 1u);
    return (unsigned short)(r >> 16);
}
__device__ __forceinline__ float bf2f(unsigned short h) {
    return __uint_as_float(((unsigned int)h) << 16);
}

__device__ __forceinline__ void gload_lds16(const unsigned short* g, unsigned short* l) {
    __builtin_amdgcn_global_load_lds(
        (const __attribute__((address_space(1))) void*)g,
        (__attribute__((address_space(3))) void*)l, 16, 0, 0);
}

// ---------------------------------------------------------------------------
// Fused prep: x split (3072 blocks) + 3 qkv-weight splits (1728) +
// o-weight split (576) + bias concat (9).
// ---------------------------------------------------------------------------
__global__ __launch_bounds__(256) void prep_kernel(
    const float* __restrict__ x,
    const float* __restrict__ qw, const float* __restrict__ kw,
    const float* __restrict__ vw, const float* __restrict__ ow,
    const float* __restrict__ qb, const float* __restrict__ kb,
    const float* __restrict__ vb,
    unsigned short* __restrict__ xh, unsigned short* __restrict__ xl,
    unsigned short* __restrict__ wqh, unsigned short* __restrict__ wql,
    unsigned short* __restrict__ woh, unsigned short* __restrict__ wol,
    float* __restrict__ bq)
{
    const int bx = blockIdx.x;
    const float* src; unsigned short *dh, *dl; int e;
    if (bx < 3072) {
        e = (bx * 256 + threadIdx.x) * 4;
        src = x; dh = xh; dl = xl;
    } else if (bx < 3072 + 1728) {
        int bb = bx - 3072; int which = bb / 576;
        e = ((bb - which * 576) * 256 + threadIdx.x) * 4;
        src = (which == 0) ? qw : (which == 1) ? kw : vw;
        dh = wqh + (size_t)which * Wn * Wn;
        dl = wql + (size_t)which * Wn * Wn;
    } else if (bx < 3072 + 1728 + 576) {
        e = ((bx - 3072 - 1728) * 256 + threadIdx.x) * 4;
        src = ow; dh = woh; dl = wol;
    } else {
        int t = (bx - 3072 - 1728 - 576) * 256 + threadIdx.x;
        if (t < Wn) bq[t] = qb[t];
        else if (t < 2 * Wn) bq[t] = kb[t - Wn];
        else if (t < 3 * Wn) bq[t] = vb[t - 2 * Wn];
        return;
    }
    int row = e / Wn, col = e - row * Wn;
    float4 v = *(const float4*)(src + (size_t)row * En + col);
    float f[4] = {v.x, v.y, v.z, v.w};
    short4v h, l;
    #pragma unroll
    for (int i = 0; i < 4; ++i) {
        unsigned short hh = f2bf_rn(f[i]);
        h[i] = (short)hh;
        l[i] = (short)f2bf_rn(f[i] - bf2f(hh));
    }
    *(short4v*)(dh + e) = h;
    *(short4v*)(dl + e) = l;
}

// ---------------------------------------------------------------------------
// QKV GEMM.  q/k: SINGLE-term bf16; v: bf16x3.  v-tiles (3x work) are
// remapped to dispatch FIRST (y bijective rotate) to cut the makespan tail.
// q/k out: bf16 [B,H,S,D]; v out: bf16 [B,H,D,S].
// ---------------------------------------------------------------------------
__global__ __launch_bounds__(256) void qkv_mfma_kernel(
    const unsigned short* __restrict__ xh, const unsigned short* __restrict__ xl,
    const unsigned short* __restrict__ wh, const unsigned short* __restrict__ wl,
    const float* __restrict__ bq,
    unsigned short* __restrict__ qh_o, unsigned short* __restrict__ kh_o,
    unsigned short* __restrict__ vt_o)
{
    __shared__ __align__(16) unsigned short Ah[128 * 32];
    __shared__ __align__(16) unsigned short Al[128 * 32];
    __shared__ __align__(16) unsigned short Bh[128 * 32];
    __shared__ __align__(16) unsigned short Bl[128 * 32];

    const int tid = threadIdx.x;
    const int wave = tid >> 6, lane = tid & 63;
    const int quad = lane >> 4, l16 = lane & 15;
    const int yy = ((int)blockIdx.y + 12) % 18;        // v-tiles first
    const int m0 = blockIdx.x * 128, n0 = yy * 128;
    const int wm = wave >> 1, wn = wave & 1;
    const int which = n0 / Wn;                 // 0=q 1=k 2=v (blocks never straddle)
    const bool full = (which == 2);

    floatx4 acc[4][4] = {};

    const unsigned short* gsrc = (wave == 0) ? xh : (wave == 1) ? xl
                               : (wave == 2) ? wh : wl;
    unsigned short* ldst = (wave == 0) ? Ah : (wave == 1) ? Al
                         : (wave == 2) ? Bh : Bl;
    const int base_row = (wave < 2) ? m0 : n0;
    const int r_in = lane >> 2;
    const int cs = (lane & 3) ^ (r_in & 3);

    for (int k0 = 0; k0 < Wn; k0 += 32) {
        if (full || wave == 0 || wave == 2) {  // Al/Bl only needed for v-blocks
            #pragma unroll
            for (int i = 0; i < 8; ++i) {
                int r = i * 16 + r_in;
                const unsigned short* gp =
                    gsrc + (size_t)(base_row + r) * Wn + k0 + cs * 8;
                gload_lds16(gp, ldst + i * 512);
            }
        }
        __syncthreads();

        short8 afh[4], afl[4], bfh[4], bfl[4];
        #pragma unroll
        for (int t = 0; t < 4; ++t) {
            int mr = wm * 64 + t * 16 + l16;
            int ca = quad ^ (mr & 3);
            afh[t] = *(const short8*)(Ah + mr * 32 + ca * 8);
            if (full) afl[t] = *(const short8*)(Al + mr * 32 + ca * 8);
            int nr = wn * 64 + t * 16 + l16;
            int cb = quad ^ (nr & 3);
            bfh[t] = *(const short8*)(Bh + nr * 32 + cb * 8);
            if (full) bfl[t] = *(const short8*)(Bl + nr * 32 + cb * 8);
        }
        #pragma unroll
        for (int mt = 0; mt < 4; ++mt)
            #pragma unroll
            for (int nt = 0; nt < 4; ++nt) {
                acc[mt][nt] = MFMA16(afh[mt], bfh[nt], acc[mt][nt]);
                if (full) {
                    acc[mt][nt] = MFMA16(afh[mt], bfl[nt], acc[mt][nt]);
                    acc[mt][nt] = MFMA16(afl[mt], bfh[nt], acc[mt][nt]);
                }
            }
        __syncthreads();
    }

    const int b = m0 >> 10;
    #pragma unroll
    for (int nt = 0; nt < 4; ++nt) {
        const int ng = n0 + wn * 64 + nt * 16 + l16;
        const float bias = bq[ng];
        const int f = ng - which * Wn;
        const int h = f >> 6, d = f & 63;
        #pragma unroll
        for (int mt = 0; mt < 4; ++mt) {
            const int mbase = m0 + wm * 64 + mt * 16 + quad * 4;
            const int s0 = mbase & (Sn - 1);
            if (which < 2) {
                unsigned short* oq = which ? kh_o : qh_o;
                size_t idx = (((size_t)(b * Hn + h)) * Sn + s0) * Dn + d;
                #pragma unroll
                for (int r = 0; r < 4; ++r)
                    oq[idx + (size_t)r * Dn] = f2bf_rn(acc[mt][nt][r] + bias);
            } else {
                size_t idx = (((size_t)(b * Hn + h)) * Dn + d) * Sn + s0;
                short4v pk;
                #pragma unroll
                for (int r = 0; r < 4; ++r)
                    pk[r] = (short)f2bf_rn(acc[mt][nt][r] + bias);
                *(short4v*)(vt_o + idx) = pk;
            }
        }
    }
}

// ---------------------------------------------------------------------------
// Fused attention, quarter-wave version: 256 threads, 4 waves; each wave owns
// a 256-key quarter of the SAME 16 q-rows.  Pr[8] (32 VGPR) instead of
// Pr[16] -> 4 waves/SIMD occupancy.  Obuf aliased onto dead Ps LDS.
// grid (64, H, B) = 3072 blocks.
// ---------------------------------------------------------------------------
__global__ __launch_bounds__(256) void attn_fused_kernel(
    const unsigned short* __restrict__ qh, const unsigned short* __restrict__ kh,
    const unsigned short* __restrict__ vt, const int* __restrict__ mask,
    float* __restrict__ attn,
    unsigned short* __restrict__ aoh, unsigned short* __restrict__ aol)
{
    // Ps (phase 1) and Obuf (epilogue) are disjoint in time: alias them.
    __shared__ __align__(16) char PsObuf[3 * 16 * 68 * 4];   // 13056 B
    __shared__ float msk[Sn];
    __shared__ float Lsum[4][16];

    unsigned short (*Ps)[16 * 72] =
        (unsigned short (*)[16 * 72])PsObuf;                  // 4 x 2304 B
    float (*Obuf)[16][68] = (float (*)[16][68])PsObuf;        // 3 x 4352 B

    const int tid = threadIdx.x;
    const int wave = tid >> 6, lane = tid & 63;
    const int quad = lane >> 4, l16 = lane & 15;
    const int qt = blockIdx.x;
    const int h = blockIdx.y, b = blockIdx.z;
    const int bh = b * Hn + h;
    const size_t kvb = (size_t)bh * Sn * Dn;
    const size_t vbase = (size_t)bh * Dn * Sn;

    {
        int4 mi = *(const int4*)(mask + b * Sn + tid * 4);
        msk[tid * 4 + 0] = (float)mi.x;
        msk[tid * 4 + 1] = (float)mi.y;
        msk[tid * 4 + 2] = (float)mi.z;
        msk[tid * 4 + 3] = (float)mi.w;
    }

    const int qrow = qt * 16 + l16;
    short8 qf[2];
    {
        const unsigned short* qp = qh + kvb + (size_t)qrow * Dn + quad * 8;
        qf[0] = *(const short8*)(qp);
        qf[1] = *(const short8*)(qp + 32);
    }
    __syncthreads();                                   // msk ready

    // ---- Phase 1: scores + exp once over this wave's 256-key quarter ----
    short8 Pr[8];                                      // static indexing only
    float lsumr[4] = {0.f, 0.f, 0.f, 0.f};
    const int kbase = wave * 256;

    #pragma unroll
    for (int kk = 0; kk < 4; ++kk) {
        const int k0 = kbase + kk * 64;
        #pragma unroll
        for (int ct = 0; ct < 4; ++ct) {
            const int key = k0 + ct * 16 + l16;
            const unsigned short* kp = kh + kvb + (size_t)key * Dn + quad * 8;
            short8 kf0 = *(const short8*)(kp);
            short8 kf1 = *(const short8*)(kp + 32);
            floatx4 acc = {0.f, 0.f, 0.f, 0.f};
            acc = MFMA16(qf[0], kf0, acc);
            acc = MFMA16(qf[1], kf1, acc);
            const float mv = msk[key];
            #pragma unroll
            for (int r = 0; r < 4; ++r) {
                const float e = __expf(acc[r] * 0.125f) * mv;
                lsumr[r] += e;
                Ps[wave][(quad * 4 + r) * 72 + ct * 16 + l16] = f2bf_rn(e);
            }
        }
        // transpose readback (wave-local LDS; in-wave ordering)
        Pr[kk * 2 + 0] = *(const short8*)&Ps[wave][l16 * 72 + quad * 8];
        Pr[kk * 2 + 1] = *(const short8*)&Ps[wave][l16 * 72 + 32 + quad * 8];
    }

    // ---- denominator: intra-wave (over keys) then cross-quarter via LDS ----
    #pragma unroll
    for (int r = 0; r < 4; ++r) {
        float v = lsumr[r];
        v += __shfl_xor(v, 1, 64);
        v += __shfl_xor(v, 2, 64);
        v += __shfl_xor(v, 4, 64);
        v += __shfl_xor(v, 8, 64);
        lsumr[r] = v;
    }
    if (l16 == 0) {
        #pragma unroll
        for (int r = 0; r < 4; ++r) Lsum[wave][quad * 4 + r] = lsumr[r];
    }
    __syncthreads();                                   // Lsum ready; Ps dead

    float li[4];
    #pragma unroll
    for (int r = 0; r < 4; ++r) {
        const float lv = Lsum[0][quad * 4 + r] + Lsum[1][quad * 4 + r]
                       + Lsum[2][quad * 4 + r] + Lsum[3][quad * 4 + r];
        li[r] = (lv > 0.f) ? 1.f / lv : 0.f;
    }
    float lt;
    {
        const float lv = Lsum[0][l16] + Lsum[1][l16] + Lsum[2][l16] + Lsum[3][l16];
        lt = (lv > 0.f) ? 1.f / lv : 0.f;
    }

    // ---- Phase 2: normalized attn stores + PV from registers ----
    floatx4 oacc[4] = {};
    float* aprow = attn + ((size_t)bh * Sn + qrow) * Sn;

    #pragma unroll
    for (int kk = 0; kk < 4; ++kk) {
        const int k0 = kbase + kk * 64;
        #pragma unroll
        for (int ksp = 0; ksp < 2; ++ksp) {
            const short8 pf = Pr[kk * 2 + ksp];
            float4 f0, f1;
            f0.x = bf2f((unsigned short)pf[0]) * lt;
            f0.y = bf2f((unsigned short)pf[1]) * lt;
            f0.z = bf2f((unsigned short)pf[2]) * lt;
            f0.w = bf2f((unsigned short)pf[3]) * lt;
            f1.x = bf2f((unsigned short)pf[4]) * lt;
            f1.y = bf2f((unsigned short)pf[5]) * lt;
            f1.z = bf2f((unsigned short)pf[6]) * lt;
            f1.w = bf2f((unsigned short)pf[7]) * lt;
            float* ap = aprow + k0 + ksp * 32 + quad * 8;
            *(float4*)(ap)     = f0;
            *(float4*)(ap + 4) = f1;
            #pragma unroll
            for (int dt = 0; dt < 4; ++dt) {
                short8 vf = *(const short8*)(vt + vbase
                              + (size_t)(dt * 16 + l16) * Sn + k0 + ksp * 32 + quad * 8);
                oacc[dt] = MFMA16(pf, vf, oacc[dt]);   // unnormalized P
            }
        }
    }

    // ---- cross-quarter O combine (Obuf aliases dead Ps) + epilogue ----
    if (wave != 0) {
        #pragma unroll
        for (int dt = 0; dt < 4; ++dt)
            #pragma unroll
            for (int r = 0; r < 4; ++r)
                Obuf[wave - 1][quad * 4 + r][dt * 16 + l16] = oacc[dt][r];
    }
    __syncthreads();
    if (wave == 0) {
        const int row0 = qt * 16 + quad * 4;
        #pragma unroll
        for (int dt = 0; dt < 4; ++dt)
            #pragma unroll
            for (int r = 0; r < 4; ++r) {
                const float o = (oacc[dt][r]
                               + Obuf[0][quad * 4 + r][dt * 16 + l16]
                               + Obuf[1][quad * 4 + r][dt * 16 + l16]
                               + Obuf[2][quad * 4 + r][dt * 16 + l16]) * li[r];
                const unsigned short hh = f2bf_rn(o);
                const size_t idx = ((size_t)b * Sn + row0 + r) * Wn + h * Dn + dt * 16 + l16;
                aoh[idx] = hh;
                aol[idx] = f2bf_rn(o - bf2f(hh));
            }
    }
}

// ---------------------------------------------------------------------------
// O projection: 64x128 tiles -> grid (64,6) = 384 blocks.
// ---------------------------------------------------------------------------
__global__ __launch_bounds__(256) void oproj_mfma_kernel(
    const unsigned short* __restrict__ aoh, const unsigned short* __restrict__ aol,
    const unsigned short* __restrict__ wh, const unsigned short* __restrict__ wl,
    const float* __restrict__ ob, float* __restrict__ out)
{
    __shared__ __align__(16) unsigned short Ah[64 * 32];
    __shared__ __align__(16) unsigned short Al[64 * 32];
    __shared__ __align__(16) unsigned short Bh[128 * 32];
    __shared__ __align__(16) unsigned short Bl[128 * 32];

    const int tid = threadIdx.x;
    const int wave = tid >> 6, lane = tid & 63;
    const int quad = lane >> 4, l16 = lane & 15;
    const int m0 = blockIdx.x * 64, n0 = blockIdx.y * 128;
    const int wm = wave >> 1, wn = wave & 1;

    floatx4 acc[2][4] = {};

    const int r_in = lane >> 2;
    const int cs = (lane & 3) ^ (r_in & 3);

    for (int k0 = 0; k0 < Wn; k0 += 32) {
        if (wave == 0) {
            #pragma unroll
            for (int i = 0; i < 4; ++i) {
                gload_lds16(aoh + (size_t)(m0 + i * 16 + r_in) * Wn + k0 + cs * 8,
                            Ah + i * 512);
                gload_lds16(aol + (size_t)(m0 + i * 16 + r_in) * Wn + k0 + cs * 8,
                            Al + i * 512);
            }
        } else if (wave == 1) {
            #pragma unroll
            for (int i = 0; i < 8; ++i)
                gload_lds16(wh + (size_t)(n0 + i * 16 + r_in) * Wn + k0 + cs * 8,
                            Bh + i * 512);
        } else if (wave == 2) {
            #pragma unroll
            for (int i = 0; i < 8; ++i)
                gload_lds16(wl + (size_t)(n0 + i * 16 + r_in) * Wn + k0 + cs * 8,
                            Bl + i * 512);
        }
        __syncthreads();

        short8 afh[2], afl[2], bfh[4], bfl[4];
        #pragma unroll
        for (int t = 0; t < 2; ++t) {
            int mr = wm * 32 + t * 16 + l16;
            int ca = quad ^ (mr & 3);
            afh[t] = *(const short8*)(Ah + mr * 32 + ca * 8);
            afl[t] = *(const short8*)(Al + mr * 32 + ca * 8);
        }
        #pragma unroll
        for (int t = 0; t < 4; ++t) {
            int nr = wn * 64 + t * 16 + l16;
            int cb = quad ^ (nr & 3);
            bfh[t] = *(const short8*)(Bh + nr * 32 + cb * 8);
            bfl[t] = *(const short8*)(Bl + nr * 32 + cb * 8);
        }
        #pragma unroll
        for (int mt = 0; mt < 2; ++mt)
            #pragma unroll
            for (int nt = 0; nt < 4; ++nt) {
                acc[mt][nt] = MFMA16(afh[mt], bfh[nt], acc[mt][nt]);
                acc[mt][nt] = MFMA16(afh[mt], bfl[nt], acc[mt][nt]);
                acc[mt][nt] = MFMA16(afl[mt], bfh[nt], acc[mt][nt]);
            }
        __syncthreads();
    }

    #pragma unroll
    for (int nt = 0; nt < 4; ++nt) {
        const int ng = n0 + wn * 64 + nt * 16 + l16;
        const float bias = ob[ng];
        #pragma unroll
        for (int mt = 0; mt < 2; ++mt) {
            const int m = m0 + wm * 32 + mt * 16 + quad * 4;
            #pragma unroll
            for (int r = 0; r < 4; ++r)
                out[(size_t)(m + r) * Wn + ng] = acc[mt][nt][r] + bias;
        }
    }
}

// ---------------------------------------------------------------------------
extern "C" void kernel_launch(void* const* d_in, const int* in_sizes, int n_in,
                              void* d_out, int out_size, void* d_ws, size_t ws_size,
                              hipStream_t stream) {
    const float* x    = (const float*)d_in[0];
    const int*   mask = (const int*)  d_in[1];
    const float* qw = (const float*)d_in[2];
    const float* qb = (const float*)d_in[3];
    const float* kw = (const float*)d_in[4];
    const float* kb = (const float*)d_in[5];
    const float* vw = (const float*)d_in[6];
    const float* vb = (const float*)d_in[7];
    const float* ow = (const float*)d_in[8];
    const float* ob = (const float*)d_in[9];

    float* out  = (float*)d_out;                       // [4096, 768]
    float* attn = out + XE;                            // [B,H,S,S]

    char* w = (char*)d_ws;
    unsigned short* xh   = (unsigned short*)w;  w += XE * 2;     // also aoh
    unsigned short* xl   = (unsigned short*)w;  w += XE * 2;     // also aol
    unsigned short* wqh  = (unsigned short*)w;  w += (size_t)3 * Wn * Wn * 2;
    unsigned short* wql  = (unsigned short*)w;  w += (size_t)3 * Wn * Wn * 2;
    unsigned short* woh  = (unsigned short*)w;  w += (size_t)Wn * Wn * 2;
    unsigned short* wol  = (unsigned short*)w;  w += (size_t)Wn * Wn * 2;
    float*          bq   = (float*)w;           w += (size_t)3 * Wn * 4;
    unsigned short* qh   = (unsigned short*)w;  w += XE * 2;
    unsigned short* kh   = (unsigned short*)w;  w += XE * 2;
    unsigned short* vt_w = (unsigned short*)w;  w += XE * 2;

    prep_kernel<<<5385, 256, 0, stream>>>(x, qw, kw, vw, ow, qb, kb, vb,
                                          xh, xl, wqh, wql, woh, wol, bq);

    qkv_mfma_kernel<<<dim3(32, 18), 256, 0, stream>>>(
        xh, xl, wqh, wql, bq, qh, kh, vt_w);

    attn_fused_kernel<<<dim3(64, Hn, Bn), 256, 0, stream>>>(
        qh, kh, vt_w, mask, attn, xh, xl);

    oproj_mfma_kernel<<<dim3(64, 6), 256, 0, stream>>>(
        xh, xl, woh, wol, ob, out);
}

// Round 6
// 384.088 us; speedup vs baseline: 1.2041x; 1.0176x over previous
//
#include <hip/hip_runtime.h>

#define Bn 4
#define Sn 1024
#define En 1024
#define Wn 768
#define Hn 12
#define Dn 64
#define XE ((size_t)Bn * Sn * Wn)   // 3,145,728

typedef __attribute__((ext_vector_type(8))) short short8;
typedef __attribute__((ext_vector_type(4))) short short4v;
typedef __attribute__((ext_vector_type(4))) float floatx4;

#define MFMA16(A, B, C) __builtin_amdgcn_mfma_f32_16x16x32_bf16(A, B, C, 0, 0, 0)

__device__ __forceinline__ unsigned short f2bf_rn(float f) {
    unsigned int u = __float_as_uint(f);
    unsigned int r = u + 0x7fffu + ((u >> 16) & 1u);
    return (unsigned short)(r >> 16);
}
__device__ __forceinline__ float bf2f(unsigned short h) {
    return __uint_as_float(((unsigned int)h) << 16);
}

__device__ __forceinline__ void gload_lds16(const unsigned short* g, unsigned short* l) {
    __builtin_amdgcn_global_load_lds(
        (const __attribute__((address_space(1))) void*)g,
        (__attribute__((address_space(3))) void*)l, 16, 0, 0);
}

// ---------------------------------------------------------------------------
// Fused prep: x hi-split (3072 blocks; lo never consumed downstream) +
// 3 qkv-weight splits (1728) + o-weight split (576) + bias concat (9).
// ---------------------------------------------------------------------------
__global__ __launch_bounds__(256) void prep_kernel(
    const float* __restrict__ x,
    const float* __restrict__ qw, const float* __restrict__ kw,
    const float* __restrict__ vw, const float* __restrict__ ow,
    const float* __restrict__ qb, const float* __restrict__ kb,
    const float* __restrict__ vb,
    unsigned short* __restrict__ xh, unsigned short* __restrict__ xl,
    unsigned short* __restrict__ wqh, unsigned short* __restrict__ wql,
    unsigned short* __restrict__ woh, unsigned short* __restrict__ wol,
    float* __restrict__ bq)
{
    const int bx = blockIdx.x;
    const float* src; unsigned short *dh, *dl; int e;
    bool lo = true;
    if (bx < 3072) {
        e = (bx * 256 + threadIdx.x) * 4;
        src = x; dh = xh; dl = xl; lo = false;         // x-lo unused
    } else if (bx < 3072 + 1728) {
        int bb = bx - 3072; int which = bb / 576;
        e = ((bb - which * 576) * 256 + threadIdx.x) * 4;
        src = (which == 0) ? qw : (which == 1) ? kw : vw;
        dh = wqh + (size_t)which * Wn * Wn;
        dl = wql + (size_t)which * Wn * Wn;
    } else if (bx < 3072 + 1728 + 576) {
        e = ((bx - 3072 - 1728) * 256 + threadIdx.x) * 4;
        src = ow; dh = woh; dl = wol;
    } else {
        int t = (bx - 3072 - 1728 - 576) * 256 + threadIdx.x;
        if (t < Wn) bq[t] = qb[t];
        else if (t < 2 * Wn) bq[t] = kb[t - Wn];
        else if (t < 3 * Wn) bq[t] = vb[t - 2 * Wn];
        return;
    }
    int row = e / Wn, col = e - row * Wn;
    float4 v = *(const float4*)(src + (size_t)row * En + col);
    float f[4] = {v.x, v.y, v.z, v.w};
    short4v h, l;
    #pragma unroll
    for (int i = 0; i < 4; ++i) {
        unsigned short hh = f2bf_rn(f[i]);
        h[i] = (short)hh;
        l[i] = (short)f2bf_rn(f[i] - bf2f(hh));
    }
    *(short4v*)(dh + e) = h;
    if (lo) *(short4v*)(dl + e) = l;
}

// ---------------------------------------------------------------------------
// QKV GEMM.  A = xh only (single bf16 activations).  q/k: 1 term (xh*wh);
// v: 2 terms (xh*wh + xh*wl) -- dropped cross terms are at/below the bf16
// output quantization of each result.  v-tiles (2x work) dispatch FIRST.
// q/k out: bf16 [B,H,S,D]; v out: bf16 [B,H,D,S].
// ---------------------------------------------------------------------------
__global__ __launch_bounds__(256) void qkv_mfma_kernel(
    const unsigned short* __restrict__ xh,
    const unsigned short* __restrict__ wh, const unsigned short* __restrict__ wl,
    const float* __restrict__ bq,
    unsigned short* __restrict__ qh_o, unsigned short* __restrict__ kh_o,
    unsigned short* __restrict__ vt_o)
{
    __shared__ __align__(16) unsigned short Ah[128 * 32];
    __shared__ __align__(16) unsigned short Bh[128 * 32];
    __shared__ __align__(16) unsigned short Bl[128 * 32];

    const int tid = threadIdx.x;
    const int wave = tid >> 6, lane = tid & 63;
    const int quad = lane >> 4, l16 = lane & 15;
    const int yy = ((int)blockIdx.y + 12) % 18;        // v-tiles first
    const int m0 = blockIdx.x * 128, n0 = yy * 128;
    const int wm = wave >> 1, wn = wave & 1;
    const int which = n0 / Wn;                 // 0=q 1=k 2=v (blocks never straddle)
    const bool full = (which == 2);

    floatx4 acc[4][4] = {};

    const int r_in = lane >> 2;
    const int cs = (lane & 3) ^ (r_in & 3);

    for (int k0 = 0; k0 < Wn; k0 += 32) {
        if (wave == 0) {
            #pragma unroll
            for (int i = 0; i < 8; ++i)
                gload_lds16(xh + (size_t)(m0 + i * 16 + r_in) * Wn + k0 + cs * 8,
                            Ah + i * 512);
        } else if (wave == 1) {
            #pragma unroll
            for (int i = 0; i < 8; ++i)
                gload_lds16(wh + (size_t)(n0 + i * 16 + r_in) * Wn + k0 + cs * 8,
                            Bh + i * 512);
        } else if (wave == 2 && full) {
            #pragma unroll
            for (int i = 0; i < 8; ++i)
                gload_lds16(wl + (size_t)(n0 + i * 16 + r_in) * Wn + k0 + cs * 8,
                            Bl + i * 512);
        }
        __syncthreads();

        short8 afh[4], bfh[4], bfl[4];
        #pragma unroll
        for (int t = 0; t < 4; ++t) {
            int mr = wm * 64 + t * 16 + l16;
            int ca = quad ^ (mr & 3);
            afh[t] = *(const short8*)(Ah + mr * 32 + ca * 8);
            int nr = wn * 64 + t * 16 + l16;
            int cb = quad ^ (nr & 3);
            bfh[t] = *(const short8*)(Bh + nr * 32 + cb * 8);
            if (full) bfl[t] = *(const short8*)(Bl + nr * 32 + cb * 8);
        }
        #pragma unroll
        for (int mt = 0; mt < 4; ++mt)
            #pragma unroll
            for (int nt = 0; nt < 4; ++nt) {
                acc[mt][nt] = MFMA16(afh[mt], bfh[nt], acc[mt][nt]);
                if (full) acc[mt][nt] = MFMA16(afh[mt], bfl[nt], acc[mt][nt]);
            }
        __syncthreads();
    }

    const int b = m0 >> 10;
    #pragma unroll
    for (int nt = 0; nt < 4; ++nt) {
        const int ng = n0 + wn * 64 + nt * 16 + l16;
        const float bias = bq[ng];
        const int f = ng - which * Wn;
        const int h = f >> 6, d = f & 63;
        #pragma unroll
        for (int mt = 0; mt < 4; ++mt) {
            const int mbase = m0 + wm * 64 + mt * 16 + quad * 4;
            const int s0 = mbase & (Sn - 1);
            if (which < 2) {
                unsigned short* oq = which ? kh_o : qh_o;
                size_t idx = (((size_t)(b * Hn + h)) * Sn + s0) * Dn + d;
                #pragma unroll
                for (int r = 0; r < 4; ++r)
                    oq[idx + (size_t)r * Dn] = f2bf_rn(acc[mt][nt][r] + bias);
            } else {
                size_t idx = (((size_t)(b * Hn + h)) * Dn + d) * Sn + s0;
                short4v pk;
                #pragma unroll
                for (int r = 0; r < 4; ++r)
                    pk[r] = (short)f2bf_rn(acc[mt][nt][r] + bias);
                *(short4v*)(vt_o + idx) = pk;
            }
        }
    }
}

// ---------------------------------------------------------------------------
// Fused attention, quarter-wave version: 256 threads, 4 waves; each wave owns
// a 256-key quarter of the SAME 16 q-rows.  Pr[8] (32 VGPR) instead of
// Pr[16] -> 4 waves/SIMD occupancy.  Obuf aliased onto dead Ps LDS.
// grid (64, H, B) = 3072 blocks.
// ---------------------------------------------------------------------------
__global__ __launch_bounds__(256) void attn_fused_kernel(
    const unsigned short* __restrict__ qh, const unsigned short* __restrict__ kh,
    const unsigned short* __restrict__ vt, const int* __restrict__ mask,
    float* __restrict__ attn,
    unsigned short* __restrict__ aoh, unsigned short* __restrict__ aol)
{
    // Ps (phase 1) and Obuf (epilogue) are disjoint in time: alias them.
    __shared__ __align__(16) char PsObuf[3 * 16 * 68 * 4];   // 13056 B
    __shared__ float msk[Sn];
    __shared__ float Lsum[4][16];

    unsigned short (*Ps)[16 * 72] =
        (unsigned short (*)[16 * 72])PsObuf;                  // 4 x 2304 B
    float (*Obuf)[16][68] = (float (*)[16][68])PsObuf;        // 3 x 4352 B

    const int tid = threadIdx.x;
    const int wave = tid >> 6, lane = tid & 63;
    const int quad = lane >> 4, l16 = lane & 15;
    const int qt = blockIdx.x;
    const int h = blockIdx.y, b = blockIdx.z;
    const int bh = b * Hn + h;
    const size_t kvb = (size_t)bh * Sn * Dn;
    const size_t vbase = (size_t)bh * Dn * Sn;

    {
        int4 mi = *(const int4*)(mask + b * Sn + tid * 4);
        msk[tid * 4 + 0] = (float)mi.x;
        msk[tid * 4 + 1] = (float)mi.y;
        msk[tid * 4 + 2] = (float)mi.z;
        msk[tid * 4 + 3] = (float)mi.w;
    }

    const int qrow = qt * 16 + l16;
    short8 qf[2];
    {
        const unsigned short* qp = qh + kvb + (size_t)qrow * Dn + quad * 8;
        qf[0] = *(const short8*)(qp);
        qf[1] = *(const short8*)(qp + 32);
    }
    __syncthreads();                                   // msk ready

    // ---- Phase 1: scores + exp once over this wave's 256-key quarter ----
    short8 Pr[8];                                      // static indexing only
    float lsumr[4] = {0.f, 0.f, 0.f, 0.f};
    const int kbase = wave * 256;

    #pragma unroll
    for (int kk = 0; kk < 4; ++kk) {
        const int k0 = kbase + kk * 64;
        #pragma unroll
        for (int ct = 0; ct < 4; ++ct) {
            const int key = k0 + ct * 16 + l16;
            const unsigned short* kp = kh + kvb + (size_t)key * Dn + quad * 8;
            short8 kf0 = *(const short8*)(kp);
            short8 kf1 = *(const short8*)(kp + 32);
            floatx4 acc = {0.f, 0.f, 0.f, 0.f};
            acc = MFMA16(qf[0], kf0, acc);
            acc = MFMA16(qf[1], kf1, acc);
            const float mv = msk[key];
            #pragma unroll
            for (int r = 0; r < 4; ++r) {
                const float e = __expf(acc[r] * 0.125f) * mv;
                lsumr[r] += e;
                Ps[wave][(quad * 4 + r) * 72 + ct * 16 + l16] = f2bf_rn(e);
            }
        }
        // transpose readback (wave-local LDS; in-wave ordering)
        Pr[kk * 2 + 0] = *(const short8*)&Ps[wave][l16 * 72 + quad * 8];
        Pr[kk * 2 + 1] = *(const short8*)&Ps[wave][l16 * 72 + 32 + quad * 8];
    }

    // ---- denominator: intra-wave (over keys) then cross-quarter via LDS ----
    #pragma unroll
    for (int r = 0; r < 4; ++r) {
        float v = lsumr[r];
        v += __shfl_xor(v, 1, 64);
        v += __shfl_xor(v, 2, 64);
        v += __shfl_xor(v, 4, 64);
        v += __shfl_xor(v, 8, 64);
        lsumr[r] = v;
    }
    if (l16 == 0) {
        #pragma unroll
        for (int r = 0; r < 4; ++r) Lsum[wave][quad * 4 + r] = lsumr[r];
    }
    __syncthreads();                                   // Lsum ready; Ps dead

    float li[4];
    #pragma unroll
    for (int r = 0; r < 4; ++r) {
        const float lv = Lsum[0][quad * 4 + r] + Lsum[1][quad * 4 + r]
                       + Lsum[2][quad * 4 + r] + Lsum[3][quad * 4 + r];
        li[r] = (lv > 0.f) ? 1.f / lv : 0.f;
    }
    float lt;
    {
        const float lv = Lsum[0][l16] + Lsum[1][l16] + Lsum[2][l16] + Lsum[3][l16];
        lt = (lv > 0.f) ? 1.f / lv : 0.f;
    }

    // ---- Phase 2: normalized attn stores + PV from registers ----
    floatx4 oacc[4] = {};
    float* aprow = attn + ((size_t)bh * Sn + qrow) * Sn;

    #pragma unroll
    for (int kk = 0; kk < 4; ++kk) {
        const int k0 = kbase + kk * 64;
        #pragma unroll
        for (int ksp = 0; ksp < 2; ++ksp) {
            const short8 pf = Pr[kk * 2 + ksp];
            float4 f0, f1;
            f0.x = bf2f((unsigned short)pf[0]) * lt;
            f0.y = bf2f((unsigned short)pf[1]) * lt;
            f0.z = bf2f((unsigned short)pf[2]) * lt;
            f0.w = bf2f((unsigned short)pf[3]) * lt;
            f1.x = bf2f((unsigned short)pf[4]) * lt;
            f1.y = bf2f((unsigned short)pf[5]) * lt;
            f1.z = bf2f((unsigned short)pf[6]) * lt;
            f1.w = bf2f((unsigned short)pf[7]) * lt;
            float* ap = aprow + k0 + ksp * 32 + quad * 8;
            *(float4*)(ap)     = f0;
            *(float4*)(ap + 4) = f1;
            #pragma unroll
            for (int dt = 0; dt < 4; ++dt) {
                short8 vf = *(const short8*)(vt + vbase
                              + (size_t)(dt * 16 + l16) * Sn + k0 + ksp * 32 + quad * 8);
                oacc[dt] = MFMA16(pf, vf, oacc[dt]);   // unnormalized P
            }
        }
    }

    // ---- cross-quarter O combine (Obuf aliases dead Ps) + epilogue ----
    if (wave != 0) {
        #pragma unroll
        for (int dt = 0; dt < 4; ++dt)
            #pragma unroll
            for (int r = 0; r < 4; ++r)
                Obuf[wave - 1][quad * 4 + r][dt * 16 + l16] = oacc[dt][r];
    }
    __syncthreads();
    if (wave == 0) {
        const int row0 = qt * 16 + quad * 4;
        #pragma unroll
        for (int dt = 0; dt < 4; ++dt)
            #pragma unroll
            for (int r = 0; r < 4; ++r) {
                const float o = (oacc[dt][r]
                               + Obuf[0][quad * 4 + r][dt * 16 + l16]
                               + Obuf[1][quad * 4 + r][dt * 16 + l16]
                               + Obuf[2][quad * 4 + r][dt * 16 + l16]) * li[r];
                const unsigned short hh = f2bf_rn(o);
                const size_t idx = ((size_t)b * Sn + row0 + r) * Wn + h * Dn + dt * 16 + l16;
                aoh[idx] = hh;
                aol[idx] = f2bf_rn(o - bf2f(hh));
            }
    }
}

// ---------------------------------------------------------------------------
// O projection: 64x128 tiles -> grid (64,6) = 384 blocks.
// ---------------------------------------------------------------------------
__global__ __launch_bounds__(256) void oproj_mfma_kernel(
    const unsigned short* __restrict__ aoh, const unsigned short* __restrict__ aol,
    const unsigned short* __restrict__ wh, const unsigned short* __restrict__ wl,
    const float* __restrict__ ob, float* __restrict__ out)
{
    __shared__ __align__(16) unsigned short Ah[64 * 32];
    __shared__ __align__(16) unsigned short Al[64 * 32];
    __shared__ __align__(16) unsigned short Bh[128 * 32];
    __shared__ __align__(16) unsigned short Bl[128 * 32];

    const int tid = threadIdx.x;
    const int wave = tid >> 6, lane = tid & 63;
    const int quad = lane >> 4, l16 = lane & 15;
    const int m0 = blockIdx.x * 64, n0 = blockIdx.y * 128;
    const int wm = wave >> 1, wn = wave & 1;

    floatx4 acc[2][4] = {};

    const int r_in = lane >> 2;
    const int cs = (lane & 3) ^ (r_in & 3);

    for (int k0 = 0; k0 < Wn; k0 += 32) {
        if (wave == 0) {
            #pragma unroll
            for (int i = 0; i < 4; ++i) {
                gload_lds16(aoh + (size_t)(m0 + i * 16 + r_in) * Wn + k0 + cs * 8,
                            Ah + i * 512);
                gload_lds16(aol + (size_t)(m0 + i * 16 + r_in) * Wn + k0 + cs * 8,
                            Al + i * 512);
            }
        } else if (wave == 1) {
            #pragma unroll
            for (int i = 0; i < 8; ++i)
                gload_lds16(wh + (size_t)(n0 + i * 16 + r_in) * Wn + k0 + cs * 8,
                            Bh + i * 512);
        } else if (wave == 2) {
            #pragma unroll
            for (int i = 0; i < 8; ++i)
                gload_lds16(wl + (size_t)(n0 + i * 16 + r_in) * Wn + k0 + cs * 8,
                            Bl + i * 512);
        }
        __syncthreads();

        short8 afh[2], afl[2], bfh[4], bfl[4];
        #pragma unroll
        for (int t = 0; t < 2; ++t) {
            int mr = wm * 32 + t * 16 + l16;
            int ca = quad ^ (mr & 3);
            afh[t] = *(const short8*)(Ah + mr * 32 + ca * 8);
            afl[t] = *(const short8*)(Al + mr * 32 + ca * 8);
        }
        #pragma unroll
        for (int t = 0; t < 4; ++t) {
            int nr = wn * 64 + t * 16 + l16;
            int cb = quad ^ (nr & 3);
            bfh[t] = *(const short8*)(Bh + nr * 32 + cb * 8);
            bfl[t] = *(const short8*)(Bl + nr * 32 + cb * 8);
        }
        #pragma unroll
        for (int mt = 0; mt < 2; ++mt)
            #pragma unroll
            for (int nt = 0; nt < 4; ++nt) {
                acc[mt][nt] = MFMA16(afh[mt], bfh[nt], acc[mt][nt]);
                acc[mt][nt] = MFMA16(afh[mt], bfl[nt], acc[mt][nt]);
                acc[mt][nt] = MFMA16(afl[mt], bfh[nt], acc[mt][nt]);
            }
        __syncthreads();
    }

    #pragma unroll
    for (int nt = 0; nt < 4; ++nt) {
        const int ng = n0 + wn * 64 + nt * 16 + l16;
        const float bias = ob[ng];
        #pragma unroll
        for (int mt = 0; mt < 2; ++mt) {
            const int m = m0 + wm * 32 + mt * 16 + quad * 4;
            #pragma unroll
            for (int r = 0; r < 4; ++r)
                out[(size_t)(m + r) * Wn + ng] = acc[mt][nt][r] + bias;
        }
    }
}

// ---------------------------------------------------------------------------
extern "C" void kernel_launch(void* const* d_in, const int* in_sizes, int n_in,
                              void* d_out, int out_size, void* d_ws, size_t ws_size,
                              hipStream_t stream) {
    const float* x    = (const float*)d_in[0];
    const int*   mask = (const int*)  d_in[1];
    const float* qw = (const float*)d_in[2];
    const float* qb = (const float*)d_in[3];
    const float* kw = (const float*)d_in[4];
    const float* kb = (const float*)d_in[5];
    const float* vw = (const float*)d_in[6];
    const float* vb = (const float*)d_in[7];
    const float* ow = (const float*)d_in[8];
    const float* ob = (const float*)d_in[9];

    float* out  = (float*)d_out;                       // [4096, 768]
    float* attn = out + XE;                            // [B,H,S,S]

    char* w = (char*)d_ws;
    unsigned short* xh   = (unsigned short*)w;  w += XE * 2;     // also aoh
    unsigned short* xl   = (unsigned short*)w;  w += XE * 2;     // aol (x-lo unused)
    unsigned short* wqh  = (unsigned short*)w;  w += (size_t)3 * Wn * Wn * 2;
    unsigned short* wql  = (unsigned short*)w;  w += (size_t)3 * Wn * Wn * 2;
    unsigned short* woh  = (unsigned short*)w;  w += (size_t)Wn * Wn * 2;
    unsigned short* wol  = (unsigned short*)w;  w += (size_t)Wn * Wn * 2;
    float*          bq   = (float*)w;           w += (size_t)3 * Wn * 4;
    unsigned short* qh   = (unsigned short*)w;  w += XE * 2;
    unsigned short* kh   = (unsigned short*)w;  w += XE * 2;
    unsigned short* vt_w = (unsigned short*)w;  w += XE * 2;

    prep_kernel<<<5385, 256, 0, stream>>>(x, qw, kw, vw, ow, qb, kb, vb,
                                          xh, xl, wqh, wql, woh, wol, bq);

    qkv_mfma_kernel<<<dim3(32, 18), 256, 0, stream>>>(
        xh, wqh, wql, bq, qh, kh, vt_w);

    attn_fused_kernel<<<dim3(64, Hn, Bn), 256, 0, stream>>>(
        qh, kh, vt_w, mask, attn, xh, xl);

    oproj_mfma_kernel<<<dim3(64, 6), 256, 0, stream>>>(
        xh, xl, woh, wol, ob, out);
}

// Round 7
// 374.435 us; speedup vs baseline: 1.2351x; 1.0258x over previous
//
#include <hip/hip_runtime.h>

#define Bn 4
#define Sn 1024
#define En 1024
#define Wn 768
#define Hn 12
#define Dn 64
#define XE ((size_t)Bn * Sn * Wn)   // 3,145,728

typedef __attribute__((ext_vector_type(8))) short short8;
typedef __attribute__((ext_vector_type(4))) short short4v;
typedef __attribute__((ext_vector_type(4))) float floatx4;

#define MFMA16(A, B, C) __builtin_amdgcn_mfma_f32_16x16x32_bf16(A, B, C, 0, 0, 0)

__device__ __forceinline__ unsigned short f2bf_rn(float f) {
    unsigned int u = __float_as_uint(f);
    unsigned int r = u + 0x7fffu + ((u >> 16) & 1u);
    return (unsigned short)(r >> 16);
}
__device__ __forceinline__ float bf2f(unsigned short h) {
    return __uint_as_float(((unsigned int)h) << 16);
}

__device__ __forceinline__ void gload_lds16(const unsigned short* g, unsigned short* l) {
    __builtin_amdgcn_global_load_lds(
        (const __attribute__((address_space(1))) void*)g,
        (__attribute__((address_space(3))) void*)l, 16, 0, 0);
}

// ---------------------------------------------------------------------------
// Fused prep: x hi-split (3072 blocks) + 3 qkv-weight splits (1728; lo only
// for v — q/k lo-weights are dead) + o-weight split (576) + bias concat (9).
// ---------------------------------------------------------------------------
__global__ __launch_bounds__(256) void prep_kernel(
    const float* __restrict__ x,
    const float* __restrict__ qw, const float* __restrict__ kw,
    const float* __restrict__ vw, const float* __restrict__ ow,
    const float* __restrict__ qb, const float* __restrict__ kb,
    const float* __restrict__ vb,
    unsigned short* __restrict__ xh, unsigned short* __restrict__ xl,
    unsigned short* __restrict__ wqh, unsigned short* __restrict__ wql,
    unsigned short* __restrict__ woh, unsigned short* __restrict__ wol,
    float* __restrict__ bq)
{
    const int bx = blockIdx.x;
    const float* src; unsigned short *dh, *dl; int e;
    bool lo = true;
    if (bx < 3072) {
        e = (bx * 256 + threadIdx.x) * 4;
        src = x; dh = xh; dl = xl; lo = false;         // x-lo unused
    } else if (bx < 3072 + 1728) {
        int bb = bx - 3072; int which = bb / 576;
        e = ((bb - which * 576) * 256 + threadIdx.x) * 4;
        src = (which == 0) ? qw : (which == 1) ? kw : vw;
        dh = wqh + (size_t)which * Wn * Wn;
        dl = wql + (size_t)which * Wn * Wn;
        lo = (which == 2);                             // q/k lo-weights dead
    } else if (bx < 3072 + 1728 + 576) {
        e = ((bx - 3072 - 1728) * 256 + threadIdx.x) * 4;
        src = ow; dh = woh; dl = wol;
    } else {
        int t = (bx - 3072 - 1728 - 576) * 256 + threadIdx.x;
        if (t < Wn) bq[t] = qb[t];
        else if (t < 2 * Wn) bq[t] = kb[t - Wn];
        else if (t < 3 * Wn) bq[t] = vb[t - 2 * Wn];
        return;
    }
    int row = e / Wn, col = e - row * Wn;
    float4 v = *(const float4*)(src + (size_t)row * En + col);
    float f[4] = {v.x, v.y, v.z, v.w};
    short4v h, l;
    #pragma unroll
    for (int i = 0; i < 4; ++i) {
        unsigned short hh = f2bf_rn(f[i]);
        h[i] = (short)hh;
        l[i] = (short)f2bf_rn(f[i] - bf2f(hh));
    }
    *(short4v*)(dh + e) = h;
    if (lo) *(short4v*)(dl + e) = l;
}

// ---------------------------------------------------------------------------
// QKV GEMM.  A = xh only.  q/k: 1 term (xh*wh); v: 2 terms (xh*wh + xh*wl).
// v-tiles (2x work) dispatch FIRST.  q/k out: bf16 [B,H,S,D]; v: [B,H,D,S].
// ---------------------------------------------------------------------------
__global__ __launch_bounds__(256) void qkv_mfma_kernel(
    const unsigned short* __restrict__ xh,
    const unsigned short* __restrict__ wh, const unsigned short* __restrict__ wl,
    const float* __restrict__ bq,
    unsigned short* __restrict__ qh_o, unsigned short* __restrict__ kh_o,
    unsigned short* __restrict__ vt_o)
{
    __shared__ __align__(16) unsigned short Ah[128 * 32];
    __shared__ __align__(16) unsigned short Bh[128 * 32];
    __shared__ __align__(16) unsigned short Bl[128 * 32];

    const int tid = threadIdx.x;
    const int wave = tid >> 6, lane = tid & 63;
    const int quad = lane >> 4, l16 = lane & 15;
    const int yy = ((int)blockIdx.y + 12) % 18;        // v-tiles first
    const int m0 = blockIdx.x * 128, n0 = yy * 128;
    const int wm = wave >> 1, wn = wave & 1;
    const int which = n0 / Wn;                 // 0=q 1=k 2=v (blocks never straddle)
    const bool full = (which == 2);

    floatx4 acc[4][4] = {};

    const int r_in = lane >> 2;
    const int cs = (lane & 3) ^ (r_in & 3);

    for (int k0 = 0; k0 < Wn; k0 += 32) {
        if (wave == 0) {
            #pragma unroll
            for (int i = 0; i < 8; ++i)
                gload_lds16(xh + (size_t)(m0 + i * 16 + r_in) * Wn + k0 + cs * 8,
                            Ah + i * 512);
        } else if (wave == 1) {
            #pragma unroll
            for (int i = 0; i < 8; ++i)
                gload_lds16(wh + (size_t)(n0 + i * 16 + r_in) * Wn + k0 + cs * 8,
                            Bh + i * 512);
        } else if (wave == 2 && full) {
            #pragma unroll
            for (int i = 0; i < 8; ++i)
                gload_lds16(wl + (size_t)(n0 + i * 16 + r_in) * Wn + k0 + cs * 8,
                            Bl + i * 512);
        }
        __syncthreads();

        short8 afh[4], bfh[4], bfl[4];
        #pragma unroll
        for (int t = 0; t < 4; ++t) {
            int mr = wm * 64 + t * 16 + l16;
            int ca = quad ^ (mr & 3);
            afh[t] = *(const short8*)(Ah + mr * 32 + ca * 8);
            int nr = wn * 64 + t * 16 + l16;
            int cb = quad ^ (nr & 3);
            bfh[t] = *(const short8*)(Bh + nr * 32 + cb * 8);
            if (full) bfl[t] = *(const short8*)(Bl + nr * 32 + cb * 8);
        }
        #pragma unroll
        for (int mt = 0; mt < 4; ++mt)
            #pragma unroll
            for (int nt = 0; nt < 4; ++nt) {
                acc[mt][nt] = MFMA16(afh[mt], bfh[nt], acc[mt][nt]);
                if (full) acc[mt][nt] = MFMA16(afh[mt], bfl[nt], acc[mt][nt]);
            }
        __syncthreads();
    }

    const int b = m0 >> 10;
    #pragma unroll
    for (int nt = 0; nt < 4; ++nt) {
        const int ng = n0 + wn * 64 + nt * 16 + l16;
        const float bias = bq[ng];
        const int f = ng - which * Wn;
        const int h = f >> 6, d = f & 63;
        #pragma unroll
        for (int mt = 0; mt < 4; ++mt) {
            const int mbase = m0 + wm * 64 + mt * 16 + quad * 4;
            const int s0 = mbase & (Sn - 1);
            if (which < 2) {
                unsigned short* oq = which ? kh_o : qh_o;
                size_t idx = (((size_t)(b * Hn + h)) * Sn + s0) * Dn + d;
                #pragma unroll
                for (int r = 0; r < 4; ++r)
                    oq[idx + (size_t)r * Dn] = f2bf_rn(acc[mt][nt][r] + bias);
            } else {
                size_t idx = (((size_t)(b * Hn + h)) * Dn + d) * Sn + s0;
                short4v pk;
                #pragma unroll
                for (int r = 0; r < 4; ++r)
                    pk[r] = (short)f2bf_rn(acc[mt][nt][r] + bias);
                *(short4v*)(vt_o + idx) = pk;
            }
        }
    }
}

// ---------------------------------------------------------------------------
// Fused attention, quarter-wave: 256 threads, 4 waves; each wave owns a
// 256-key quarter of the SAME 16 q-rows.  Phase 2 bounces normalized fp32 P
// through a wave-local PsF tile so attn stores are fully coalesced
// (4 rows x 256B contiguous per float4 instruction).  O emitted hi-only.
// grid (64, H, B) = 3072 blocks.
// ---------------------------------------------------------------------------
__global__ __launch_bounds__(256) void attn_fused_kernel(
    const unsigned short* __restrict__ qh, const unsigned short* __restrict__ kh,
    const unsigned short* __restrict__ vt, const int* __restrict__ mask,
    float* __restrict__ attn, unsigned short* __restrict__ aoh)
{
    // Ps (phase 1), PsF (phase 2), Obuf (epilogue) are disjoint in time.
    __shared__ __align__(16) char PsObuf[4 * 16 * 68 * 4];   // 17408 B
    __shared__ float msk[Sn];
    __shared__ float Lsum[4][16];

    unsigned short (*Ps)[16 * 72] =
        (unsigned short (*)[16 * 72])PsObuf;                  // 4 x 2304 B
    float (*PsF)[16][68] = (float (*)[16][68])PsObuf;         // 4 x 4352 B
    float (*Obuf)[16][68] = (float (*)[16][68])PsObuf;        // 3 x 4352 B

    const int tid = threadIdx.x;
    const int wave = tid >> 6, lane = tid & 63;
    const int quad = lane >> 4, l16 = lane & 15;
    const int qt = blockIdx.x;
    const int h = blockIdx.y, b = blockIdx.z;
    const int bh = b * Hn + h;
    const size_t kvb = (size_t)bh * Sn * Dn;
    const size_t vbase = (size_t)bh * Dn * Sn;

    {
        int4 mi = *(const int4*)(mask + b * Sn + tid * 4);
        msk[tid * 4 + 0] = (float)mi.x;
        msk[tid * 4 + 1] = (float)mi.y;
        msk[tid * 4 + 2] = (float)mi.z;
        msk[tid * 4 + 3] = (float)mi.w;
    }

    const int qrow = qt * 16 + l16;
    short8 qf[2];
    {
        const unsigned short* qp = qh + kvb + (size_t)qrow * Dn + quad * 8;
        qf[0] = *(const short8*)(qp);
        qf[1] = *(const short8*)(qp + 32);
    }
    __syncthreads();                                   // msk ready

    // ---- Phase 1: scores + exp once over this wave's 256-key quarter ----
    short8 Pr[8];                                      // static indexing only
    float lsumr[4] = {0.f, 0.f, 0.f, 0.f};
    const int kbase = wave * 256;

    #pragma unroll
    for (int kk = 0; kk < 4; ++kk) {
        const int k0 = kbase + kk * 64;
        #pragma unroll
        for (int ct = 0; ct < 4; ++ct) {
            const int key = k0 + ct * 16 + l16;
            const unsigned short* kp = kh + kvb + (size_t)key * Dn + quad * 8;
            short8 kf0 = *(const short8*)(kp);
            short8 kf1 = *(const short8*)(kp + 32);
            floatx4 acc = {0.f, 0.f, 0.f, 0.f};
            acc = MFMA16(qf[0], kf0, acc);
            acc = MFMA16(qf[1], kf1, acc);
            const float mv = msk[key];
            #pragma unroll
            for (int r = 0; r < 4; ++r) {
                const float e = __expf(acc[r] * 0.125f) * mv;
                lsumr[r] += e;
                Ps[wave][(quad * 4 + r) * 72 + ct * 16 + l16] = f2bf_rn(e);
            }
        }
        // transpose readback (wave-local LDS; in-wave ordering)
        Pr[kk * 2 + 0] = *(const short8*)&Ps[wave][l16 * 72 + quad * 8];
        Pr[kk * 2 + 1] = *(const short8*)&Ps[wave][l16 * 72 + 32 + quad * 8];
    }

    // ---- denominator: intra-wave (over keys) then cross-quarter via LDS ----
    #pragma unroll
    for (int r = 0; r < 4; ++r) {
        float v = lsumr[r];
        v += __shfl_xor(v, 1, 64);
        v += __shfl_xor(v, 2, 64);
        v += __shfl_xor(v, 4, 64);
        v += __shfl_xor(v, 8, 64);
        lsumr[r] = v;
    }
    if (l16 == 0) {
        #pragma unroll
        for (int r = 0; r < 4; ++r) Lsum[wave][quad * 4 + r] = lsumr[r];
    }
    __syncthreads();                                   // Lsum ready; Ps dead

    float li[4];
    #pragma unroll
    for (int r = 0; r < 4; ++r) {
        const float lv = Lsum[0][quad * 4 + r] + Lsum[1][quad * 4 + r]
                       + Lsum[2][quad * 4 + r] + Lsum[3][quad * 4 + r];
        li[r] = (lv > 0.f) ? 1.f / lv : 0.f;
    }
    float lt;                                          // inverse for row l16
    {
        const float lv = Lsum[0][l16] + Lsum[1][l16] + Lsum[2][l16] + Lsum[3][l16];
        lt = (lv > 0.f) ? 1.f / lv : 0.f;
    }

    // ---- Phase 2: PV from registers + coalesced attn stores via PsF ----
    floatx4 oacc[4] = {};
    float* abase = attn + ((size_t)bh * Sn + qt * 16) * Sn;

    #pragma unroll
    for (int kk = 0; kk < 4; ++kk) {
        const int k0 = kbase + kk * 64;
        #pragma unroll
        for (int ksp = 0; ksp < 2; ++ksp) {
            const short8 pf = Pr[kk * 2 + ksp];
            float4 f0, f1;
            f0.x = bf2f((unsigned short)pf[0]) * lt;
            f0.y = bf2f((unsigned short)pf[1]) * lt;
            f0.z = bf2f((unsigned short)pf[2]) * lt;
            f0.w = bf2f((unsigned short)pf[3]) * lt;
            f1.x = bf2f((unsigned short)pf[4]) * lt;
            f1.y = bf2f((unsigned short)pf[5]) * lt;
            f1.z = bf2f((unsigned short)pf[6]) * lt;
            f1.w = bf2f((unsigned short)pf[7]) * lt;
            *(float4*)&PsF[wave][l16][ksp * 32 + quad * 8]     = f0;
            *(float4*)&PsF[wave][l16][ksp * 32 + quad * 8 + 4] = f1;
            #pragma unroll
            for (int dt = 0; dt < 4; ++dt) {
                short8 vf = *(const short8*)(vt + vbase
                              + (size_t)(dt * 16 + l16) * Sn + k0 + ksp * 32 + quad * 8);
                oacc[dt] = MFMA16(pf, vf, oacc[dt]);   // unnormalized P
            }
        }
        // coalesced stores: rows on quad, keys on l16 (wave-local ordering)
        #pragma unroll
        for (int rb = 0; rb < 4; ++rb) {
            float4 v4 = *(const float4*)&PsF[wave][rb * 4 + quad][l16 * 4];
            *(float4*)(abase + (size_t)(rb * 4 + quad) * Sn + k0 + l16 * 4) = v4;
        }
    }

    // ---- cross-quarter O combine (Obuf aliases dead Ps/PsF) + epilogue ----
    __syncthreads();                                   // PsF dead
    if (wave != 0) {
        #pragma unroll
        for (int dt = 0; dt < 4; ++dt)
            #pragma unroll
            for (int r = 0; r < 4; ++r)
                Obuf[wave - 1][quad * 4 + r][dt * 16 + l16] = oacc[dt][r];
    }
    __syncthreads();
    if (wave == 0) {
        const int row0 = qt * 16 + quad * 4;
        #pragma unroll
        for (int dt = 0; dt < 4; ++dt)
            #pragma unroll
            for (int r = 0; r < 4; ++r) {
                const float o = (oacc[dt][r]
                               + Obuf[0][quad * 4 + r][dt * 16 + l16]
                               + Obuf[1][quad * 4 + r][dt * 16 + l16]
                               + Obuf[2][quad * 4 + r][dt * 16 + l16]) * li[r];
                const size_t idx = ((size_t)b * Sn + row0 + r) * Wn + h * Dn + dt * 16 + l16;
                aoh[idx] = f2bf_rn(o);                 // O hi-only
            }
    }
}

// ---------------------------------------------------------------------------
// O projection, 2-term (AO hi x W hi/lo): 64x128 tiles -> grid (64,6).
// ---------------------------------------------------------------------------
__global__ __launch_bounds__(256) void oproj_mfma_kernel(
    const unsigned short* __restrict__ aoh,
    const unsigned short* __restrict__ wh, const unsigned short* __restrict__ wl,
    const float* __restrict__ ob, float* __restrict__ out)
{
    __shared__ __align__(16) unsigned short Ah[64 * 32];
    __shared__ __align__(16) unsigned short Bh[128 * 32];
    __shared__ __align__(16) unsigned short Bl[128 * 32];

    const int tid = threadIdx.x;
    const int wave = tid >> 6, lane = tid & 63;
    const int quad = lane >> 4, l16 = lane & 15;
    const int m0 = blockIdx.x * 64, n0 = blockIdx.y * 128;
    const int wm = wave >> 1, wn = wave & 1;

    floatx4 acc[2][4] = {};

    const int r_in = lane >> 2;
    const int cs = (lane & 3) ^ (r_in & 3);

    for (int k0 = 0; k0 < Wn; k0 += 32) {
        if (wave == 0) {
            #pragma unroll
            for (int i = 0; i < 4; ++i)
                gload_lds16(aoh + (size_t)(m0 + i * 16 + r_in) * Wn + k0 + cs * 8,
                            Ah + i * 512);
        } else if (wave == 1) {
            #pragma unroll
            for (int i = 0; i < 8; ++i)
                gload_lds16(wh + (size_t)(n0 + i * 16 + r_in) * Wn + k0 + cs * 8,
                            Bh + i * 512);
        } else if (wave == 2) {
            #pragma unroll
            for (int i = 0; i < 8; ++i)
                gload_lds16(wl + (size_t)(n0 + i * 16 + r_in) * Wn + k0 + cs * 8,
                            Bl + i * 512);
        }
        __syncthreads();

        short8 afh[2], bfh[4], bfl[4];
        #pragma unroll
        for (int t = 0; t < 2; ++t) {
            int mr = wm * 32 + t * 16 + l16;
            int ca = quad ^ (mr & 3);
            afh[t] = *(const short8*)(Ah + mr * 32 + ca * 8);
        }
        #pragma unroll
        for (int t = 0; t < 4; ++t) {
            int nr = wn * 64 + t * 16 + l16;
            int cb = quad ^ (nr & 3);
            bfh[t] = *(const short8*)(Bh + nr * 32 + cb * 8);
            bfl[t] = *(const short8*)(Bl + nr * 32 + cb * 8);
        }
        #pragma unroll
        for (int mt = 0; mt < 2; ++mt)
            #pragma unroll
            for (int nt = 0; nt < 4; ++nt) {
                acc[mt][nt] = MFMA16(afh[mt], bfh[nt], acc[mt][nt]);
                acc[mt][nt] = MFMA16(afh[mt], bfl[nt], acc[mt][nt]);
            }
        __syncthreads();
    }

    #pragma unroll
    for (int nt = 0; nt < 4; ++nt) {
        const int ng = n0 + wn * 64 + nt * 16 + l16;
        const float bias = ob[ng];
        #pragma unroll
        for (int mt = 0; mt < 2; ++mt) {
            const int m = m0 + wm * 32 + mt * 16 + quad * 4;
            #pragma unroll
            for (int r = 0; r < 4; ++r)
                out[(size_t)(m + r) * Wn + ng] = acc[mt][nt][r] + bias;
        }
    }
}

// ---------------------------------------------------------------------------
extern "C" void kernel_launch(void* const* d_in, const int* in_sizes, int n_in,
                              void* d_out, int out_size, void* d_ws, size_t ws_size,
                              hipStream_t stream) {
    const float* x    = (const float*)d_in[0];
    const int*   mask = (const int*)  d_in[1];
    const float* qw = (const float*)d_in[2];
    const float* qb = (const float*)d_in[3];
    const float* kw = (const float*)d_in[4];
    const float* kb = (const float*)d_in[5];
    const float* vw = (const float*)d_in[6];
    const float* vb = (const float*)d_in[7];
    const float* ow = (const float*)d_in[8];
    const float* ob = (const float*)d_in[9];

    float* out  = (float*)d_out;                       // [4096, 768]
    float* attn = out + XE;                            // [B,H,S,S]

    char* w = (char*)d_ws;
    unsigned short* xh   = (unsigned short*)w;  w += XE * 2;     // also aoh
    unsigned short* xl   = (unsigned short*)w;  w += XE * 2;     // unused now
    unsigned short* wqh  = (unsigned short*)w;  w += (size_t)3 * Wn * Wn * 2;
    unsigned short* wql  = (unsigned short*)w;  w += (size_t)3 * Wn * Wn * 2;
    unsigned short* woh  = (unsigned short*)w;  w += (size_t)Wn * Wn * 2;
    unsigned short* wol  = (unsigned short*)w;  w += (size_t)Wn * Wn * 2;
    float*          bq   = (float*)w;           w += (size_t)3 * Wn * 4;
    unsigned short* qh   = (unsigned short*)w;  w += XE * 2;
    unsigned short* kh   = (unsigned short*)w;  w += XE * 2;
    unsigned short* vt_w = (unsigned short*)w;  w += XE * 2;

    prep_kernel<<<5385, 256, 0, stream>>>(x, qw, kw, vw, ow, qb, kb, vb,
                                          xh, xl, wqh, wql, woh, wol, bq);

    qkv_mfma_kernel<<<dim3(32, 18), 256, 0, stream>>>(
        xh, wqh, wql, bq, qh, kh, vt_w);

    attn_fused_kernel<<<dim3(64, Hn, Bn), 256, 0, stream>>>(
        qh, kh, vt_w, mask, attn, xh);

    oproj_mfma_kernel<<<dim3(64, 6), 256, 0, stream>>>(
        xh, woh, wol, ob, out);
}

// Round 8
// 371.794 us; speedup vs baseline: 1.2439x; 1.0071x over previous
//
#include <hip/hip_runtime.h>

#define Bn 4
#define Sn 1024
#define En 1024
#define Wn 768
#define Hn 12
#define Dn 64
#define XE ((size_t)Bn * Sn * Wn)   // 3,145,728

typedef __attribute__((ext_vector_type(8))) short short8;
typedef __attribute__((ext_vector_type(4))) short short4v;
typedef __attribute__((ext_vector_type(4))) float floatx4;

#define MFMA16(A, B, C) __builtin_amdgcn_mfma_f32_16x16x32_bf16(A, B, C, 0, 0, 0)

__device__ __forceinline__ unsigned short f2bf_rn(float f) {
    unsigned int u = __float_as_uint(f);
    unsigned int r = u + 0x7fffu + ((u >> 16) & 1u);
    return (unsigned short)(r >> 16);
}
__device__ __forceinline__ float bf2f(unsigned short h) {
    return __uint_as_float(((unsigned int)h) << 16);
}

__device__ __forceinline__ void gload_lds16(const unsigned short* g, unsigned short* l) {
    __builtin_amdgcn_global_load_lds(
        (const __attribute__((address_space(1))) void*)g,
        (__attribute__((address_space(3))) void*)l, 16, 0, 0);
}

// ---------------------------------------------------------------------------
// Fused prep: x hi-split (3072 blocks) + 3 qkv-weight splits (1728; lo only
// for v — q/k lo-weights are dead) + o-weight split (576) + bias concat (9).
// ---------------------------------------------------------------------------
__global__ __launch_bounds__(256) void prep_kernel(
    const float* __restrict__ x,
    const float* __restrict__ qw, const float* __restrict__ kw,
    const float* __restrict__ vw, const float* __restrict__ ow,
    const float* __restrict__ qb, const float* __restrict__ kb,
    const float* __restrict__ vb,
    unsigned short* __restrict__ xh, unsigned short* __restrict__ xl,
    unsigned short* __restrict__ wqh, unsigned short* __restrict__ wql,
    unsigned short* __restrict__ woh, unsigned short* __restrict__ wol,
    float* __restrict__ bq)
{
    const int bx = blockIdx.x;
    const float* src; unsigned short *dh, *dl; int e;
    bool lo = true;
    if (bx < 3072) {
        e = (bx * 256 + threadIdx.x) * 4;
        src = x; dh = xh; dl = xl; lo = false;         // x-lo unused
    } else if (bx < 3072 + 1728) {
        int bb = bx - 3072; int which = bb / 576;
        e = ((bb - which * 576) * 256 + threadIdx.x) * 4;
        src = (which == 0) ? qw : (which == 1) ? kw : vw;
        dh = wqh + (size_t)which * Wn * Wn;
        dl = wql + (size_t)which * Wn * Wn;
        lo = (which == 2);                             // q/k lo-weights dead
    } else if (bx < 3072 + 1728 + 576) {
        e = ((bx - 3072 - 1728) * 256 + threadIdx.x) * 4;
        src = ow; dh = woh; dl = wol;
    } else {
        int t = (bx - 3072 - 1728 - 576) * 256 + threadIdx.x;
        if (t < Wn) bq[t] = qb[t];
        else if (t < 2 * Wn) bq[t] = kb[t - Wn];
        else if (t < 3 * Wn) bq[t] = vb[t - 2 * Wn];
        return;
    }
    int row = e / Wn, col = e - row * Wn;
    float4 v = *(const float4*)(src + (size_t)row * En + col);
    float f[4] = {v.x, v.y, v.z, v.w};
    short4v h, l;
    #pragma unroll
    for (int i = 0; i < 4; ++i) {
        unsigned short hh = f2bf_rn(f[i]);
        h[i] = (short)hh;
        l[i] = (short)f2bf_rn(f[i] - bf2f(hh));
    }
    *(short4v*)(dh + e) = h;
    if (lo) *(short4v*)(dl + e) = l;
}

// ---------------------------------------------------------------------------
// QKV GEMM.  A = xh only.  q/k: 1 term (xh*wh); v: 2 terms (xh*wh + xh*wl).
// v-tiles (2x work) dispatch FIRST.  q/k out: bf16 [B,H,S,D]; v: [B,H,D,S].
// (No XCD swizzle here: v-tiles' 2x work would concentrate on a few XCDs.)
// ---------------------------------------------------------------------------
__global__ __launch_bounds__(256) void qkv_mfma_kernel(
    const unsigned short* __restrict__ xh,
    const unsigned short* __restrict__ wh, const unsigned short* __restrict__ wl,
    const float* __restrict__ bq,
    unsigned short* __restrict__ qh_o, unsigned short* __restrict__ kh_o,
    unsigned short* __restrict__ vt_o)
{
    __shared__ __align__(16) unsigned short Ah[128 * 32];
    __shared__ __align__(16) unsigned short Bh[128 * 32];
    __shared__ __align__(16) unsigned short Bl[128 * 32];

    const int tid = threadIdx.x;
    const int wave = tid >> 6, lane = tid & 63;
    const int quad = lane >> 4, l16 = lane & 15;
    const int yy = ((int)blockIdx.y + 12) % 18;        // v-tiles first
    const int m0 = blockIdx.x * 128, n0 = yy * 128;
    const int wm = wave >> 1, wn = wave & 1;
    const int which = n0 / Wn;                 // 0=q 1=k 2=v (blocks never straddle)
    const bool full = (which == 2);

    floatx4 acc[4][4] = {};

    const int r_in = lane >> 2;
    const int cs = (lane & 3) ^ (r_in & 3);

    for (int k0 = 0; k0 < Wn; k0 += 32) {
        if (wave == 0) {
            #pragma unroll
            for (int i = 0; i < 8; ++i)
                gload_lds16(xh + (size_t)(m0 + i * 16 + r_in) * Wn + k0 + cs * 8,
                            Ah + i * 512);
        } else if (wave == 1) {
            #pragma unroll
            for (int i = 0; i < 8; ++i)
                gload_lds16(wh + (size_t)(n0 + i * 16 + r_in) * Wn + k0 + cs * 8,
                            Bh + i * 512);
        } else if (wave == 2 && full) {
            #pragma unroll
            for (int i = 0; i < 8; ++i)
                gload_lds16(wl + (size_t)(n0 + i * 16 + r_in) * Wn + k0 + cs * 8,
                            Bl + i * 512);
        }
        __syncthreads();

        short8 afh[4], bfh[4], bfl[4];
        #pragma unroll
        for (int t = 0; t < 4; ++t) {
            int mr = wm * 64 + t * 16 + l16;
            int ca = quad ^ (mr & 3);
            afh[t] = *(const short8*)(Ah + mr * 32 + ca * 8);
            int nr = wn * 64 + t * 16 + l16;
            int cb = quad ^ (nr & 3);
            bfh[t] = *(const short8*)(Bh + nr * 32 + cb * 8);
            if (full) bfl[t] = *(const short8*)(Bl + nr * 32 + cb * 8);
        }
        #pragma unroll
        for (int mt = 0; mt < 4; ++mt)
            #pragma unroll
            for (int nt = 0; nt < 4; ++nt) {
                acc[mt][nt] = MFMA16(afh[mt], bfh[nt], acc[mt][nt]);
                if (full) acc[mt][nt] = MFMA16(afh[mt], bfl[nt], acc[mt][nt]);
            }
        __syncthreads();
    }

    const int b = m0 >> 10;
    #pragma unroll
    for (int nt = 0; nt < 4; ++nt) {
        const int ng = n0 + wn * 64 + nt * 16 + l16;
        const float bias = bq[ng];
        const int f = ng - which * Wn;
        const int h = f >> 6, d = f & 63;
        #pragma unroll
        for (int mt = 0; mt < 4; ++mt) {
            const int mbase = m0 + wm * 64 + mt * 16 + quad * 4;
            const int s0 = mbase & (Sn - 1);
            if (which < 2) {
                unsigned short* oq = which ? kh_o : qh_o;
                size_t idx = (((size_t)(b * Hn + h)) * Sn + s0) * Dn + d;
                #pragma unroll
                for (int r = 0; r < 4; ++r)
                    oq[idx + (size_t)r * Dn] = f2bf_rn(acc[mt][nt][r] + bias);
            } else {
                size_t idx = (((size_t)(b * Hn + h)) * Dn + d) * Sn + s0;
                short4v pk;
                #pragma unroll
                for (int r = 0; r < 4; ++r)
                    pk[r] = (short)f2bf_rn(acc[mt][nt][r] + bias);
                *(short4v*)(vt_o + idx) = pk;
            }
        }
    }
}

// ---------------------------------------------------------------------------
// Fused attention, quarter-wave, XCD-swizzled: bijective chunked remap so the
// 64 qt-blocks sharing one (b,h)'s K/V all land on ONE XCD (6 bh-pairs/XCD,
// 1.5 MB K/V resident in its 4 MB L2) instead of replicating fetches 8x.
// grid (64, H, B) = 3072 blocks (3072 % 8 == 0 -> bijective).
// ---------------------------------------------------------------------------
__global__ __launch_bounds__(256) void attn_fused_kernel(
    const unsigned short* __restrict__ qh, const unsigned short* __restrict__ kh,
    const unsigned short* __restrict__ vt, const int* __restrict__ mask,
    float* __restrict__ attn, unsigned short* __restrict__ aoh)
{
    // Ps (phase 1), PsF (phase 2), Obuf (epilogue) are disjoint in time.
    __shared__ __align__(16) char PsObuf[4 * 16 * 68 * 4];   // 17408 B
    __shared__ float msk[Sn];
    __shared__ float Lsum[4][16];

    unsigned short (*Ps)[16 * 72] =
        (unsigned short (*)[16 * 72])PsObuf;                  // 4 x 2304 B
    float (*PsF)[16][68] = (float (*)[16][68])PsObuf;         // 4 x 4352 B
    float (*Obuf)[16][68] = (float (*)[16][68])PsObuf;        // 3 x 4352 B

    const int tid = threadIdx.x;
    const int wave = tid >> 6, lane = tid & 63;
    const int quad = lane >> 4, l16 = lane & 15;

    // XCD-aware chunked remap (T1): launched flat%8 = XCD id; flat/8 = slot.
    const int flat = (int)blockIdx.x + 64 * ((int)blockIdx.y + Hn * (int)blockIdx.z);
    const int logical = (flat & 7) * 384 + (flat >> 3);       // 3072/8 = 384
    const int qt = logical & 63;
    const int bhg = logical >> 6;                             // 0..47
    const int h = bhg % Hn, b = bhg / Hn;

    const int bh = b * Hn + h;
    const size_t kvb = (size_t)bh * Sn * Dn;
    const size_t vbase = (size_t)bh * Dn * Sn;

    {
        int4 mi = *(const int4*)(mask + b * Sn + tid * 4);
        msk[tid * 4 + 0] = (float)mi.x;
        msk[tid * 4 + 1] = (float)mi.y;
        msk[tid * 4 + 2] = (float)mi.z;
        msk[tid * 4 + 3] = (float)mi.w;
    }

    const int qrow = qt * 16 + l16;
    short8 qf[2];
    {
        const unsigned short* qp = qh + kvb + (size_t)qrow * Dn + quad * 8;
        qf[0] = *(const short8*)(qp);
        qf[1] = *(const short8*)(qp + 32);
    }
    __syncthreads();                                   // msk ready

    // ---- Phase 1: scores + exp once over this wave's 256-key quarter ----
    short8 Pr[8];                                      // static indexing only
    float lsumr[4] = {0.f, 0.f, 0.f, 0.f};
    const int kbase = wave * 256;

    #pragma unroll
    for (int kk = 0; kk < 4; ++kk) {
        const int k0 = kbase + kk * 64;
        #pragma unroll
        for (int ct = 0; ct < 4; ++ct) {
            const int key = k0 + ct * 16 + l16;
            const unsigned short* kp = kh + kvb + (size_t)key * Dn + quad * 8;
            short8 kf0 = *(const short8*)(kp);
            short8 kf1 = *(const short8*)(kp + 32);
            floatx4 acc = {0.f, 0.f, 0.f, 0.f};
            acc = MFMA16(qf[0], kf0, acc);
            acc = MFMA16(qf[1], kf1, acc);
            const float mv = msk[key];
            #pragma unroll
            for (int r = 0; r < 4; ++r) {
                const float e = __expf(acc[r] * 0.125f) * mv;
                lsumr[r] += e;
                Ps[wave][(quad * 4 + r) * 72 + ct * 16 + l16] = f2bf_rn(e);
            }
        }
        // transpose readback (wave-local LDS; in-wave ordering)
        Pr[kk * 2 + 0] = *(const short8*)&Ps[wave][l16 * 72 + quad * 8];
        Pr[kk * 2 + 1] = *(const short8*)&Ps[wave][l16 * 72 + 32 + quad * 8];
    }

    // ---- denominator: intra-wave (over keys) then cross-quarter via LDS ----
    #pragma unroll
    for (int r = 0; r < 4; ++r) {
        float v = lsumr[r];
        v += __shfl_xor(v, 1, 64);
        v += __shfl_xor(v, 2, 64);
        v += __shfl_xor(v, 4, 64);
        v += __shfl_xor(v, 8, 64);
        lsumr[r] = v;
    }
    if (l16 == 0) {
        #pragma unroll
        for (int r = 0; r < 4; ++r) Lsum[wave][quad * 4 + r] = lsumr[r];
    }
    __syncthreads();                                   // Lsum ready; Ps dead

    float li[4];
    #pragma unroll
    for (int r = 0; r < 4; ++r) {
        const float lv = Lsum[0][quad * 4 + r] + Lsum[1][quad * 4 + r]
                       + Lsum[2][quad * 4 + r] + Lsum[3][quad * 4 + r];
        li[r] = (lv > 0.f) ? 1.f / lv : 0.f;
    }
    float lt;                                          // inverse for row l16
    {
        const float lv = Lsum[0][l16] + Lsum[1][l16] + Lsum[2][l16] + Lsum[3][l16];
        lt = (lv > 0.f) ? 1.f / lv : 0.f;
    }

    // ---- Phase 2: PV from registers + coalesced attn stores via PsF ----
    floatx4 oacc[4] = {};
    float* abase = attn + ((size_t)bh * Sn + qt * 16) * Sn;

    #pragma unroll
    for (int kk = 0; kk < 4; ++kk) {
        const int k0 = kbase + kk * 64;
        #pragma unroll
        for (int ksp = 0; ksp < 2; ++ksp) {
            const short8 pf = Pr[kk * 2 + ksp];
            float4 f0, f1;
            f0.x = bf2f((unsigned short)pf[0]) * lt;
            f0.y = bf2f((unsigned short)pf[1]) * lt;
            f0.z = bf2f((unsigned short)pf[2]) * lt;
            f0.w = bf2f((unsigned short)pf[3]) * lt;
            f1.x = bf2f((unsigned short)pf[4]) * lt;
            f1.y = bf2f((unsigned short)pf[5]) * lt;
            f1.z = bf2f((unsigned short)pf[6]) * lt;
            f1.w = bf2f((unsigned short)pf[7]) * lt;
            *(float4*)&PsF[wave][l16][ksp * 32 + quad * 8]     = f0;
            *(float4*)&PsF[wave][l16][ksp * 32 + quad * 8 + 4] = f1;
            #pragma unroll
            for (int dt = 0; dt < 4; ++dt) {
                short8 vf = *(const short8*)(vt + vbase
                              + (size_t)(dt * 16 + l16) * Sn + k0 + ksp * 32 + quad * 8);
                oacc[dt] = MFMA16(pf, vf, oacc[dt]);   // unnormalized P
            }
        }
        // coalesced stores: rows on quad, keys on l16 (wave-local ordering)
        #pragma unroll
        for (int rb = 0; rb < 4; ++rb) {
            float4 v4 = *(const float4*)&PsF[wave][rb * 4 + quad][l16 * 4];
            *(float4*)(abase + (size_t)(rb * 4 + quad) * Sn + k0 + l16 * 4) = v4;
        }
    }

    // ---- cross-quarter O combine (Obuf aliases dead Ps/PsF) + epilogue ----
    __syncthreads();                                   // PsF dead
    if (wave != 0) {
        #pragma unroll
        for (int dt = 0; dt < 4; ++dt)
            #pragma unroll
            for (int r = 0; r < 4; ++r)
                Obuf[wave - 1][quad * 4 + r][dt * 16 + l16] = oacc[dt][r];
    }
    __syncthreads();
    if (wave == 0) {
        const int row0 = qt * 16 + quad * 4;
        #pragma unroll
        for (int dt = 0; dt < 4; ++dt)
            #pragma unroll
            for (int r = 0; r < 4; ++r) {
                const float o = (oacc[dt][r]
                               + Obuf[0][quad * 4 + r][dt * 16 + l16]
                               + Obuf[1][quad * 4 + r][dt * 16 + l16]
                               + Obuf[2][quad * 4 + r][dt * 16 + l16]) * li[r];
                const size_t idx = ((size_t)b * Sn + row0 + r) * Wn + h * Dn + dt * 16 + l16;
                aoh[idx] = f2bf_rn(o);                 // O hi-only
            }
    }
}

// ---------------------------------------------------------------------------
// O projection, 2-term (AO hi x W hi/lo), XCD-swizzled: same-panel blocks
// co-located per XCD (384 % 8 == 0, uniform work -> balanced).
// 64x128 tiles -> grid (64,6).
// ---------------------------------------------------------------------------
__global__ __launch_bounds__(256) void oproj_mfma_kernel(
    const unsigned short* __restrict__ aoh,
    const unsigned short* __restrict__ wh, const unsigned short* __restrict__ wl,
    const float* __restrict__ ob, float* __restrict__ out)
{
    __shared__ __align__(16) unsigned short Ah[64 * 32];
    __shared__ __align__(16) unsigned short Bh[128 * 32];
    __shared__ __align__(16) unsigned short Bl[128 * 32];

    const int tid = threadIdx.x;
    const int wave = tid >> 6, lane = tid & 63;
    const int quad = lane >> 4, l16 = lane & 15;

    const int flat = (int)blockIdx.x + 64 * (int)blockIdx.y;
    const int logical = (flat & 7) * 48 + (flat >> 3);        // 384/8 = 48
    const int m0 = (logical & 63) * 64, n0 = (logical >> 6) * 128;

    const int wm = wave >> 1, wn = wave & 1;

    floatx4 acc[2][4] = {};

    const int r_in = lane >> 2;
    const int cs = (lane & 3) ^ (r_in & 3);

    for (int k0 = 0; k0 < Wn; k0 += 32) {
        if (wave == 0) {
            #pragma unroll
            for (int i = 0; i < 4; ++i)
                gload_lds16(aoh + (size_t)(m0 + i * 16 + r_in) * Wn + k0 + cs * 8,
                            Ah + i * 512);
        } else if (wave == 1) {
            #pragma unroll
            for (int i = 0; i < 8; ++i)
                gload_lds16(wh + (size_t)(n0 + i * 16 + r_in) * Wn + k0 + cs * 8,
                            Bh + i * 512);
        } else if (wave == 2) {
            #pragma unroll
            for (int i = 0; i < 8; ++i)
                gload_lds16(wl + (size_t)(n0 + i * 16 + r_in) * Wn + k0 + cs * 8,
                            Bl + i * 512);
        }
        __syncthreads();

        short8 afh[2], bfh[4], bfl[4];
        #pragma unroll
        for (int t = 0; t < 2; ++t) {
            int mr = wm * 32 + t * 16 + l16;
            int ca = quad ^ (mr & 3);
            afh[t] = *(const short8*)(Ah + mr * 32 + ca * 8);
        }
        #pragma unroll
        for (int t = 0; t < 4; ++t) {
            int nr = wn * 64 + t * 16 + l16;
            int cb = quad ^ (nr & 3);
            bfh[t] = *(const short8*)(Bh + nr * 32 + cb * 8);
            bfl[t] = *(const short8*)(Bl + nr * 32 + cb * 8);
        }
        #pragma unroll
        for (int mt = 0; mt < 2; ++mt)
            #pragma unroll
            for (int nt = 0; nt < 4; ++nt) {
                acc[mt][nt] = MFMA16(afh[mt], bfh[nt], acc[mt][nt]);
                acc[mt][nt] = MFMA16(afh[mt], bfl[nt], acc[mt][nt]);
            }
        __syncthreads();
    }

    #pragma unroll
    for (int nt = 0; nt < 4; ++nt) {
        const int ng = n0 + wn * 64 + nt * 16 + l16;
        const float bias = ob[ng];
        #pragma unroll
        for (int mt = 0; mt < 2; ++mt) {
            const int m = m0 + wm * 32 + mt * 16 + quad * 4;
            #pragma unroll
            for (int r = 0; r < 4; ++r)
                out[(size_t)(m + r) * Wn + ng] = acc[mt][nt][r] + bias;
        }
    }
}

// ---------------------------------------------------------------------------
extern "C" void kernel_launch(void* const* d_in, const int* in_sizes, int n_in,
                              void* d_out, int out_size, void* d_ws, size_t ws_size,
                              hipStream_t stream) {
    const float* x    = (const float*)d_in[0];
    const int*   mask = (const int*)  d_in[1];
    const float* qw = (const float*)d_in[2];
    const float* qb = (const float*)d_in[3];
    const float* kw = (const float*)d_in[4];
    const float* kb = (const float*)d_in[5];
    const float* vw = (const float*)d_in[6];
    const float* vb = (const float*)d_in[7];
    const float* ow = (const float*)d_in[8];
    const float* ob = (const float*)d_in[9];

    float* out  = (float*)d_out;                       // [4096, 768]
    float* attn = out + XE;                            // [B,H,S,S]

    char* w = (char*)d_ws;
    unsigned short* xh   = (unsigned short*)w;  w += XE * 2;     // also aoh
    unsigned short* xl   = (unsigned short*)w;  w += XE * 2;     // unused now
    unsigned short* wqh  = (unsigned short*)w;  w += (size_t)3 * Wn * Wn * 2;
    unsigned short* wql  = (unsigned short*)w;  w += (size_t)3 * Wn * Wn * 2;
    unsigned short* woh  = (unsigned short*)w;  w += (size_t)Wn * Wn * 2;
    unsigned short* wol  = (unsigned short*)w;  w += (size_t)Wn * Wn * 2;
    float*          bq   = (float*)w;           w += (size_t)3 * Wn * 4;
    unsigned short* qh   = (unsigned short*)w;  w += XE * 2;
    unsigned short* kh   = (unsigned short*)w;  w += XE * 2;
    unsigned short* vt_w = (unsigned short*)w;  w += XE * 2;

    prep_kernel<<<5385, 256, 0, stream>>>(x, qw, kw, vw, ow, qb, kb, vb,
                                          xh, xl, wqh, wql, woh, wol, bq);

    qkv_mfma_kernel<<<dim3(32, 18), 256, 0, stream>>>(
        xh, wqh, wql, bq, qh, kh, vt_w);

    attn_fused_kernel<<<dim3(64, Hn, Bn), 256, 0, stream>>>(
        qh, kh, vt_w, mask, attn, xh);

    oproj_mfma_kernel<<<dim3(64, 6), 256, 0, stream>>>(
        xh, woh, wol, ob, out);
}